// Round 5
// baseline (376.466 us; speedup 1.0000x reference)
//
#include <hip/hip_runtime.h>
#include <hip/hip_bf16.h>
#include <stdint.h>

// ---------------------------------------------------------------------------
// MultiHeadAttention on MI355X (gfx950).
// b=2, n=1024, DIM=1024, H=16, dh=64.  Outputs: out (2M f32) ++ attn (33.5M f32).
// GEMMs: bf16 MFMA 16x16x32, hi/lo split (3 MFMAs) => ~fp32 accuracy.
// R6: single-pass softmax + F fixup table.
// R7: LDS group-XOR swizzle everywhere (bank conflicts 3.15M -> ~0).
// R8: k_gemm_qkv retiled BACK to 128x128 (R7's 128x64 halved MFMA:staging
//     density 6->4; tile-space data says 128^2 >> 128x64 at this structure;
//     384 blocks still 2-deep resident on half the CUs).  k_pv BK 32->64
//     (two swizzled 32-col sub-tiles/stage): barriers/block 64 -> 32 with
//     24 MFMAs between barrier pairs.
// ---------------------------------------------------------------------------

#define NB   2
#define SEQ  1024
#define CDIM 1024
#define NH   16
#define HD   64
#define ROWS (NB*SEQ)          // 2048
#define ATT_SCALE 0.125f       // 64^-0.5

typedef __attribute__((ext_vector_type(8))) short bf16x8;
typedef __attribute__((ext_vector_type(4))) float f32x4;

#define MFMA16(a,b,c) __builtin_amdgcn_mfma_f32_16x16x32_bf16((a),(b),(c),0,0,0)

static __device__ __forceinline__ unsigned short f2bf(float f) {
  uint32_t x = __builtin_bit_cast(uint32_t, f);
  return (unsigned short)((x + 0x7fffu + ((x >> 16) & 1u)) >> 16);   // RTN-even
}
static __device__ __forceinline__ float bf2f(unsigned short u) {
  uint32_t x = ((uint32_t)u) << 16;
  return __builtin_bit_cast(float, x);
}

// async global->LDS DMA, 16B/lane; lds dest = wave-uniform base + lane*16
static __device__ __forceinline__ void gl_lds16(const unsigned short* g,
                                                unsigned short* l) {
  __builtin_amdgcn_global_load_lds(
      (const __attribute__((address_space(1))) unsigned int*)g,
      (__attribute__((address_space(3))) unsigned int*)l,
      16, 0, 0);
}

// ---------------------------------------------------------------------------
// K0: fp32 -> bf16 hi/lo split for x and concatenated W = [Wq; Wkv; Wp]
// ---------------------------------------------------------------------------
__global__ __launch_bounds__(256) void k_convert(
    const float* __restrict__ x, const float* __restrict__ Wq,
    const float* __restrict__ Wkv, const float* __restrict__ Wp,
    unsigned short* __restrict__ Xhi, unsigned short* __restrict__ Xlo,
    unsigned short* __restrict__ Whi, unsigned short* __restrict__ Wlo)
{
  const int NX = ROWS * CDIM;
  const int NW = 4096 * CDIM;
  int i = blockIdx.x * 256 + threadIdx.x;
  if (i < NX) {
    float f = x[i];
    unsigned short h = f2bf(f);
    Xhi[i] = h; Xlo[i] = f2bf(f - bf2f(h));
  } else if (i < NX + NW) {
    int w = i - NX;
    int j = w >> 10, c = w & 1023;
    float f = (j < 1024) ? Wq[(size_t)j*1024 + c]
            : (j < 3072) ? Wkv[(size_t)(j-1024)*1024 + c]
                         : Wp[(size_t)(j-3072)*1024 + c];
    unsigned short h = f2bf(f);
    Whi[w] = h; Wlo[w] = f2bf(f - bf2f(h));
  }
}

// ---------------------------------------------------------------------------
// Templated NT-GEMM core (split bf16, BK=32, wave grid WM x WN).
// LDS layout [row][32 u16] with group-XOR swizzle: 16B group g of row r
// lives at physical group g ^ ((r>>1)&3).
// ---------------------------------------------------------------------------
struct EpiQKV {
  const float* bq; const float* bkv;
  unsigned short *Qhi, *Qlo, *Khi, *Klo, *Vthi, *Vtlo;
  __device__ __forceinline__ void operator()(int m, int n, float v) const {
    if (n < 1024) {                       // Q (pre-scaled by ATT_SCALE)
      v = (v + bq[n]) * ATT_SCALE;
      unsigned short h = f2bf(v);
      size_t o = (size_t)m*1024 + n;
      Qhi[o] = h; Qlo[o] = f2bf(v - bf2f(h));
    } else if (n < 2048) {                // K
      v += bkv[n - 1024];
      size_t o = (size_t)m*1024 + (n - 1024);
      unsigned short h = f2bf(v);
      Khi[o] = h; Klo[o] = f2bf(v - bf2f(h));
    } else {                              // V -> transposed [b][h][d][m]
      v += bkv[n - 1024];
      int c = n - 2048;
      int hh = c >> 6, d = c & 63;
      int b = m >> 10, mm = m & 1023;
      size_t o = ((size_t)((b*NH + hh)*HD + d))*SEQ + mm;
      unsigned short h = f2bf(v);
      Vthi[o] = h; Vtlo[o] = f2bf(v - bf2f(h));
    }
  }
};
struct EpiOut {
  const float* bp; float* out;
  __device__ __forceinline__ void operator()(int m, int n, float v) const {
    out[(size_t)m*1024 + n] = v + bp[n];
  }
};

template <int BM, int BN, int WM, int WN, class Epi>
__device__ __forceinline__ void gemm_core(
    const unsigned short* __restrict__ Ahi, const unsigned short* __restrict__ Alo, int lda,
    const unsigned short* __restrict__ Bhi, const unsigned short* __restrict__ Blo, int ldb,
    int K, const Epi& epi)
{
  constexpr int WAVES = WM*WN;
  constexpr int FM = BM/(WM*16), FN = BN/(WN*16);
  constexpr int CA = BM/16, CB = BN/16;
  constexpr int TOT = 2*(CA+CB);
  __shared__ unsigned short sAh[BM*32], sAl[BM*32], sBh[BN*32], sBl[BN*32];
  const int tid  = threadIdx.x;
  const int lane = tid & 63, wave = tid >> 6;
  const int wm = wave % WM, wn = wave / WM;
  const int bn = blockIdx.x * BN, bm = blockIdx.y * BM;
  const int r = lane & 15, q = lane >> 4;
  const int crow = lane >> 2;
  const int cgsw = ((lane & 3) ^ ((crow >> 1) & 3)) * 8;   // swizzled src group
  const int qsw = (q ^ ((r >> 1) & 3)) * 8;                // swizzled read group

  f32x4 acc[FM][FN];
  #pragma unroll
  for (int i = 0; i < FM; i++)
    #pragma unroll
    for (int j = 0; j < FN; j++) {
      acc[i][j][0]=0.f; acc[i][j][1]=0.f; acc[i][j][2]=0.f; acc[i][j][3]=0.f;
    }

  for (int k0 = 0; k0 < K; k0 += 32) {
    #pragma unroll
    for (int t = 0; t < TOT/WAVES; t++) {
      int c = wave + t*WAVES;
      const unsigned short* gb; unsigned short* sb; int rr, grow, ld;
      if (c < CA)            { gb=Ahi; sb=sAh; rr=c;         grow=bm; ld=lda; }
      else if (c < 2*CA)     { gb=Alo; sb=sAl; rr=c-CA;      grow=bm; ld=lda; }
      else if (c < 2*CA+CB)  { gb=Bhi; sb=sBh; rr=c-2*CA;    grow=bn; ld=ldb; }
      else                   { gb=Blo; sb=sBl; rr=c-2*CA-CB; grow=bn; ld=ldb; }
      int row = rr*16 + crow;
      gl_lds16(gb + (size_t)(grow + row)*ld + k0 + cgsw, sb + rr*512);
    }
    __syncthreads();
    bf16x8 ah[FM], al[FM], bh[FN], bl[FN];
    #pragma unroll
    for (int i = 0; i < FM; i++) {
      int oa = (wm*(BM/WM) + i*16 + r)*32 + qsw;
      ah[i] = *(const bf16x8*)(sAh + oa);
      al[i] = *(const bf16x8*)(sAl + oa);
    }
    #pragma unroll
    for (int j = 0; j < FN; j++) {
      int ob = (wn*(BN/WN) + j*16 + r)*32 + qsw;
      bh[j] = *(const bf16x8*)(sBh + ob);
      bl[j] = *(const bf16x8*)(sBl + ob);
    }
    #pragma unroll
    for (int i = 0; i < FM; i++)
      #pragma unroll
      for (int j = 0; j < FN; j++) {
        acc[i][j] = MFMA16(ah[i], bh[j], acc[i][j]);
        acc[i][j] = MFMA16(ah[i], bl[j], acc[i][j]);
        acc[i][j] = MFMA16(al[i], bh[j], acc[i][j]);
      }
    __syncthreads();
  }
  #pragma unroll
  for (int i = 0; i < FM; i++)
    #pragma unroll
    for (int j = 0; j < FN; j++)
      #pragma unroll
      for (int t = 0; t < 4; t++)
        epi(bm + wm*(BM/WM) + i*16 + q*4 + t, bn + wn*(BN/WN) + j*16 + r, acc[i][j][t]);
}

__global__ __launch_bounds__(256) void k_gemm_qkv(
    const unsigned short* Xhi, const unsigned short* Xlo,
    const unsigned short* Whi, const unsigned short* Wlo,
    const float* bq, const float* bkv,
    unsigned short* Qhi, unsigned short* Qlo,
    unsigned short* Khi, unsigned short* Klo,
    unsigned short* Vthi, unsigned short* Vtlo)
{
  EpiQKV e{bq, bkv, Qhi, Qlo, Khi, Klo, Vthi, Vtlo};
  gemm_core<128,128,2,2>(Xhi, Xlo, CDIM, Whi, Wlo, CDIM, CDIM, e);
}

__global__ __launch_bounds__(512) void k_gemm_out(
    const unsigned short* OAhi, const unsigned short* OAlo,
    const unsigned short* Wphi, const unsigned short* Wplo,
    const float* bp, float* out)
{
  EpiOut e{bp, out};
  gemm_core<128,64,4,2>(OAhi, OAlo, CDIM, Wphi, Wplo, CDIM, CDIM, e);
}

// ---------------------------------------------------------------------------
// K23: SINGLE-pass softmax -> u16 P (chunk-max quantized) + fixup table F.
// Block = 32 n-rows x one (b,h); 512 thr (8 waves).  K streamed ONCE in
// 128-m chunks (double-buffered, XOR-swizzled LDS).  mfma(K,Q): lane holds
// 4 m-values per nf.  Per chunk: row-wide max via shfl + LDS partials
// (redm double-buffered => 1 barrier/chunk); quantize vs running max;
// record m_c.  End: F[b,h,n,c] = exp(m_c - m_fin)/S;  prob = stored * F.
// ---------------------------------------------------------------------------
__global__ __launch_bounds__(512, 4) void k_logits_softmax(
    const unsigned short* __restrict__ Qhi, const unsigned short* __restrict__ Qlo,
    const unsigned short* __restrict__ Khi, const unsigned short* __restrict__ Klo,
    unsigned short* __restrict__ P, float* __restrict__ F)
{
  const int nt = blockIdx.x, h = blockIdx.y, b = blockIdx.z;
  const int n0 = nt*32;
  const int col0 = h*HD;
  __shared__ unsigned short sQ[2*32*64];       // [plane][32n x 64k] swizzled 8K
  __shared__ unsigned short sK[2][2*128*64];   // [buf][plane][128m x 64k] 64K
  __shared__ float redm[2][8][32];             // per-chunk wave partial max
  __shared__ float reds[8][32];                // final sum partials
  __shared__ float musd[32][8];                // m used per (row, chunk)
  const int tid = threadIdx.x, lane = tid & 63, wave = tid >> 6;
  const int r = lane & 15, q = lane >> 4;
  const int drow = lane >> 3, dseg = (lane & 7) ^ drow;   // DMA swizzle
  const int sw = r & 7;                                   // read swizzle
  const size_t qrow0 = (size_t)b*SEQ + n0;
  const size_t krow0 = (size_t)b*SEQ;

  auto stageK = [&](int c, int buf) {
    unsigned short* dst = sK[buf];
    #pragma unroll
    for (int u = 0; u < 4; u++) {
      int cc = wave*4 + u;                 // 0..31
      int p = cc >> 4, t = cc & 15;
      const unsigned short* g = p ? Klo : Khi;
      gl_lds16(g + (krow0 + (size_t)c*128 + t*8 + drow)*CDIM + col0 + dseg*8,
               dst + p*8192 + t*512);
    }
  };

  {   // stage Q (once) + K chunk 0
    int p = wave >> 2, t = wave & 3;
    const unsigned short* g = p ? Qlo : Qhi;
    gl_lds16(g + (qrow0 + t*8 + drow)*CDIM + col0 + dseg*8,
             sQ + p*2048 + t*512);
    stageK(0, 0);
  }
  __syncthreads();

  // Q fragments live in registers for the whole kernel
  bf16x8 qh[2][2], ql[2][2];
  #pragma unroll
  for (int nf = 0; nf < 2; nf++)
    #pragma unroll
    for (int ks = 0; ks < 2; ks++) {
      int phys = (nf*16 + r)*64 + (((ks*4 + q) ^ sw))*8;
      qh[nf][ks] = *(const bf16x8*)(sQ + phys);
      ql[nf][ks] = *(const bf16x8*)(sQ + 2048 + phys);
    }

  const int mb = wave*16;
  float m_run[2] = {-1e30f, -1e30f}, s_run[2] = {0.f, 0.f};
  const size_t pbase = ((size_t)(b*NH + h)*SEQ + n0)*SEQ;

  for (int c = 0; c < 8; c++) {
    if (c < 7) stageK(c+1, (c+1)&1);
    const unsigned short* cur = sK[c&1];
    bf16x8 kh[2], kl[2];
    #pragma unroll
    for (int ks = 0; ks < 2; ks++) {
      int phys = (mb + r)*64 + (((ks*4 + q) ^ sw))*8;
      kh[ks] = *(const bf16x8*)(cur + phys);
      kl[ks] = *(const bf16x8*)(cur + 8192 + phys);
    }
    f32x4 acc[2];
    #pragma unroll
    for (int nf = 0; nf < 2; nf++) {
      acc[nf][0]=0.f; acc[nf][1]=0.f; acc[nf][2]=0.f; acc[nf][3]=0.f;
      #pragma unroll
      for (int ks = 0; ks < 2; ks++) {
        acc[nf] = MFMA16(kh[ks], qh[nf][ks], acc[nf]);
        acc[nf] = MFMA16(kl[ks], qh[nf][ks], acc[nf]);
        acc[nf] = MFMA16(kh[ks], ql[nf][ks], acc[nf]);
      }
    }
    // wave-level row-chunk max (reduce over q groups)
    float wmax[2];
    #pragma unroll
    for (int nf = 0; nf < 2; nf++) {
      float v = fmaxf(fmaxf(acc[nf][0], acc[nf][1]), fmaxf(acc[nf][2], acc[nf][3]));
      v = fmaxf(v, __shfl_xor(v, 16));
      v = fmaxf(v, __shfl_xor(v, 32));
      wmax[nf] = v;
    }
    if (q == 0) { redm[c&1][wave][r] = wmax[0]; redm[c&1][wave][16+r] = wmax[1]; }
    __syncthreads();                       // 1 barrier/chunk
    #pragma unroll
    for (int nf = 0; nf < 2; nf++) {
      int row = nf*16 + r;
      float mc = redm[c&1][0][row];
      #pragma unroll
      for (int w2 = 1; w2 < 8; w2++) mc = fmaxf(mc, redm[c&1][w2][row]);
      float mnew = fmaxf(m_run[nf], mc);
      unsigned s0 = (unsigned)(__expf(acc[nf][0]-mnew)*65535.f + 0.5f);
      unsigned s1 = (unsigned)(__expf(acc[nf][1]-mnew)*65535.f + 0.5f);
      unsigned s2 = (unsigned)(__expf(acc[nf][2]-mnew)*65535.f + 0.5f);
      unsigned s3 = (unsigned)(__expf(acc[nf][3]-mnew)*65535.f + 0.5f);
      *(uint2*)(P + pbase + (size_t)row*SEQ + c*128 + mb + q*4) =
          make_uint2(s0 | (s1 << 16), s2 | (s3 << 16));
      s_run[nf] = s_run[nf]*__expf(m_run[nf]-mnew) + (float)(s0+s1+s2+s3);
      m_run[nf] = mnew;
      if (wave == 0 && q == 0) musd[row][c] = mnew;
    }
  }

  // ---- final sum reduction + F table
  #pragma unroll
  for (int nf = 0; nf < 2; nf++) {
    float s = s_run[nf];
    s += __shfl_xor(s, 16);
    s += __shfl_xor(s, 32);
    if (q == 0) reds[wave][nf*16 + r] = s;
  }
  __syncthreads();
  if (tid < 32) {
    int row = tid;
    float S = 0.f;
    #pragma unroll
    for (int w2 = 0; w2 < 8; w2++) S += reds[w2][row];
    float mfin = musd[row][7];
    float inv = 1.0f / S;
    size_t fb = ((size_t)(b*NH + h)*SEQ + n0 + row)*8;
    #pragma unroll
    for (int c = 0; c < 8; c++)
      F[fb + c] = __expf(musd[row][c] - mfin) * inv;
  }
}

// ---------------------------------------------------------------------------
// K_attn: dequant-transpose P[b][h][n][m] u16 * F -> attn[b][n][m][h] f32.
// One thread per (b,n,m): 16 coalesced u16 loads + 16 L2-hot F loads,
// 4 contiguous float4 stores.
// ---------------------------------------------------------------------------
__global__ __launch_bounds__(256) void k_attn_write(
    const unsigned short* __restrict__ P, const float* __restrict__ F,
    float* __restrict__ attn)
{
  int T = blockIdx.x*256 + threadIdx.x;
  int b = T >> 20, rem = T & 1048575;
  int n = rem >> 10, m = rem & 1023;
  int c = m >> 7;
  const size_t pb = ((size_t)(b*NH)*SEQ + n)*SEQ + m;
  const size_t fb = ((size_t)(b*NH)*SEQ + n)*8 + c;
  float v[16];
  #pragma unroll
  for (int h = 0; h < 16; h++)
    v[h] = (float)P[pb + (size_t)h*SEQ*SEQ] * F[fb + (size_t)h*SEQ*8];
  size_t ob = ((size_t)(b*SEQ + n)*SEQ + m)*16;
  #pragma unroll
  for (int g = 0; g < 4; g++)
    *(float4*)(attn + ob + g*4) = make_float4(v[g*4], v[g*4+1], v[g*4+2], v[g*4+3]);
}

// ---------------------------------------------------------------------------
// K4: PV gemm per (b,h):  OA[n][d] = sum_c F[n][c] * sum_{m in c} P_u16 * V
// 64n x 64d per block (512 blocks); exact byte-split planes of stored u16;
// per-chunk fold accF += acc * F.  BK=64 as two swizzled 32-col sub-tiles:
// barriers/block 64 -> 32, 24 MFMAs between barrier pairs.
// ---------------------------------------------------------------------------
__global__ __launch_bounds__(256) void k_pv(
    const unsigned short* __restrict__ P, const float* __restrict__ F,
    const unsigned short* __restrict__ Vthi, const unsigned short* __restrict__ Vtlo,
    unsigned short* __restrict__ OAhi, unsigned short* __restrict__ OAlo)
{
  int nt = blockIdx.x, h = blockIdx.y, b = blockIdx.z;
  int n0 = nt * 64;
  __shared__ unsigned short sPa[2][64*32], sPb[2][64*32];
  __shared__ unsigned short sVh[2][64*32], sVl[2][64*32];
  const int tid = threadIdx.x, lane = tid & 63, wave = tid >> 6;
  const int wm = wave & 1, wn = wave >> 1;
  const int r = lane & 15, q = lane >> 4;
  const int crow = lane >> 2;
  const int cgsw = ((lane & 3) ^ ((crow >> 1) & 3)) * 8;   // swizzled src group
  const int qsw = (q ^ ((r >> 1) & 3)) * 8;                // swizzled read group
  const size_t pbase = ((size_t)(b*NH + h))*SEQ*SEQ;
  const size_t vbase = ((size_t)(b*NH + h))*HD*SEQ;
  const size_t fbase = ((size_t)(b*NH + h))*SEQ*8;

  f32x4 acc[2][2], accF[2][2];
  #pragma unroll
  for (int i = 0; i < 2; i++)
    #pragma unroll
    for (int j = 0; j < 2; j++) {
      acc[i][j][0]=0.f; acc[i][j][1]=0.f; acc[i][j][2]=0.f; acc[i][j][3]=0.f;
      accF[i][j][0]=0.f; accF[i][j][1]=0.f; accF[i][j][2]=0.f; accF[i][j][3]=0.f;
    }

  for (int k0 = 0; k0 < SEQ; k0 += 64) {
    #pragma unroll
    for (int kk = 0; kk < 2; kk++) {
      #pragma unroll
      for (int t = 0; t < 2; t++) {
        int c = wave + t*4;
        const unsigned short* gb = (c < 4) ? Vthi : Vtlo;
        unsigned short* sb = (c < 4) ? sVh[kk] : sVl[kk];
        int rr = c & 3;
        int row = rr*16 + crow;
        gl_lds16(gb + vbase + (size_t)row*SEQ + k0 + kk*32 + cgsw, sb + rr*512);
      }
    }
    {
      int row = tid >> 2, g = tid & 3, ch = g * 8;
      int gp = (g ^ ((row >> 1) & 3)) * 8;                 // swizzled LDS slot
      #pragma unroll
      for (int kk = 0; kk < 2; kk++) {
        uint4 v = *(const uint4*)(P + pbase + (size_t)(n0 + row)*SEQ + k0 + kk*32 + ch);
        unsigned int wds[4] = {v.x, v.y, v.z, v.w};
        unsigned int pa[4], pb4[4];
        #pragma unroll
        for (int e = 0; e < 4; e++) {
          unsigned int lo16 = wds[e] & 0xFFFFu;
          unsigned int hi16 = wds[e] >> 16;
          unsigned int a0 = __builtin_bit_cast(uint32_t, (float)(lo16 & 0xFF00u)) >> 16;
          unsigned int b0 = __builtin_bit_cast(uint32_t, (float)(lo16 & 0x00FFu)) >> 16;
          unsigned int a1 = __builtin_bit_cast(uint32_t, (float)(hi16 & 0xFF00u)) >> 16;
          unsigned int b1 = __builtin_bit_cast(uint32_t, (float)(hi16 & 0x00FFu)) >> 16;
          pa[e]  = a0 | (a1 << 16);
          pb4[e] = b0 | (b1 << 16);
        }
        *(uint4*)(sPa[kk] + row*32 + gp) = make_uint4(pa[0],pa[1],pa[2],pa[3]);
        *(uint4*)(sPb[kk] + row*32 + gp) = make_uint4(pb4[0],pb4[1],pb4[2],pb4[3]);
      }
    }
    __syncthreads();
    #pragma unroll
    for (int kk = 0; kk < 2; kk++) {
      bf16x8 pa[2], pb2[2], vh[2], vl[2];
      #pragma unroll
      for (int i = 0; i < 2; i++) {
        int off = (wm*32 + i*16 + r)*32 + qsw;
        pa[i]  = *(const bf16x8*)(sPa[kk] + off);
        pb2[i] = *(const bf16x8*)(sPb[kk] + off);
      }
      #pragma unroll
      for (int j = 0; j < 2; j++) {
        int off = (wn*32 + j*16 + r)*32 + qsw;
        vh[j] = *(const bf16x8*)(sVh[kk] + off);
        vl[j] = *(const bf16x8*)(sVl[kk] + off);
      }
      #pragma unroll
      for (int i = 0; i < 2; i++)
        #pragma unroll
        for (int j = 0; j < 2; j++) {
          acc[i][j] = MFMA16(pa[i],  vh[j], acc[i][j]);
          acc[i][j] = MFMA16(pb2[i], vh[j], acc[i][j]);
          acc[i][j] = MFMA16(pa[i],  vl[j], acc[i][j]);
        }
    }
    if ((k0 & 127) == 64) {                // end of 128-m chunk: fold with F
      int c = k0 >> 7;
      #pragma unroll
      for (int i = 0; i < 2; i++)
        #pragma unroll
        for (int t = 0; t < 4; t++) {
          int nn = n0 + wm*32 + i*16 + q*4 + t;
          float Fv = F[fbase + (size_t)nn*8 + c];
          #pragma unroll
          for (int j = 0; j < 2; j++) {
            accF[i][j][t] += acc[i][j][t] * Fv;
            acc[i][j][t] = 0.f;
          }
        }
    }
    __syncthreads();
  }
  #pragma unroll
  for (int i = 0; i < 2; i++)
    #pragma unroll
    for (int t = 0; t < 4; t++) {
      int nn = n0 + wm*32 + i*16 + q*4 + t;
      #pragma unroll
      for (int j = 0; j < 2; j++) {
        int d = wn*32 + j*16 + r;
        float val = accF[i][j][t];
        size_t o = (size_t)(b*SEQ + nn)*CDIM + h*HD + d;
        unsigned short hb = f2bf(val);
        OAhi[o] = hb; OAlo[o] = f2bf(val - bf2f(hb));
      }
    }
}

// ---------------------------------------------------------------------------
extern "C" void kernel_launch(void* const* d_in, const int* in_sizes, int n_in,
                              void* d_out, int out_size, void* d_ws, size_t ws_size,
                              hipStream_t stream)
{
  const float* x   = (const float*)d_in[0];
  const float* Wq  = (const float*)d_in[1];
  const float* bq  = (const float*)d_in[2];
  const float* Wkv = (const float*)d_in[3];
  const float* bkv = (const float*)d_in[4];
  const float* Wp  = (const float*)d_in[5];
  const float* bp  = (const float*)d_in[6];

  float* out  = (float*)d_out;
  float* attn = out + (size_t)ROWS*CDIM;

  char* w = (char*)d_ws;
  unsigned short* Xhi  = (unsigned short*)w; w += (size_t)ROWS*CDIM*2;
  unsigned short* Xlo  = (unsigned short*)w; w += (size_t)ROWS*CDIM*2;
  unsigned short* Whi  = (unsigned short*)w; w += (size_t)4096*CDIM*2;
  unsigned short* Wlo  = (unsigned short*)w; w += (size_t)4096*CDIM*2;
  unsigned short* Qhi  = (unsigned short*)w; w += (size_t)ROWS*CDIM*2;
  unsigned short* Qlo  = (unsigned short*)w; w += (size_t)ROWS*CDIM*2;
  unsigned short* Khi  = (unsigned short*)w; w += (size_t)ROWS*CDIM*2;
  unsigned short* Klo  = (unsigned short*)w; w += (size_t)ROWS*CDIM*2;
  unsigned short* Vthi = (unsigned short*)w; w += (size_t)NB*NH*HD*SEQ*2;
  unsigned short* Vtlo = (unsigned short*)w; w += (size_t)NB*NH*HD*SEQ*2;
  unsigned short* OAhi = (unsigned short*)w; w += (size_t)ROWS*CDIM*2;
  unsigned short* OAlo = (unsigned short*)w; w += (size_t)ROWS*CDIM*2;
  unsigned short* P    = (unsigned short*)w; w += (size_t)NB*NH*SEQ*SEQ*2;
  float*          Ftab = (float*)w;          w += (size_t)NB*NH*SEQ*8*4;

  k_convert<<<dim3((ROWS*CDIM + 4096*CDIM)/256), 256, 0, stream>>>(
      x, Wq, Wkv, Wp, Xhi, Xlo, Whi, Wlo);

  k_gemm_qkv<<<dim3(3072/128, 2048/128), 256, 0, stream>>>(
      Xhi, Xlo, Whi, Wlo, bq, bkv, Qhi, Qlo, Khi, Klo, Vthi, Vtlo);

  k_logits_softmax<<<dim3(SEQ/32, NH, NB), 512, 0, stream>>>(
      Qhi, Qlo, Khi, Klo, P, Ftab);

  k_pv<<<dim3(SEQ/64, NH, NB), 256, 0, stream>>>(P, Ftab, Vthi, Vtlo, OAhi, OAlo);

  k_gemm_out<<<dim3(1024/64, 2048/128), 512, 0, stream>>>(
      OAhi, OAlo, Whi + (size_t)3072*CDIM, Wlo + (size_t)3072*CDIM, bp, out);

  k_attn_write<<<dim3((NB*SEQ*SEQ)/256), 256, 0, stream>>>(P, Ftab, attn);
}

// Round 7
// 359.659 us; speedup vs baseline: 1.0467x; 1.0467x over previous
//
#include <hip/hip_runtime.h>
#include <hip/hip_bf16.h>
#include <stdint.h>

// ---------------------------------------------------------------------------
// MultiHeadAttention on MI355X (gfx950).
// b=2, n=1024, DIM=1024, H=16, dh=64.  Outputs: out (2M f32) ++ attn (33.5M f32).
// GEMMs: bf16 MFMA 16x16x32, hi/lo split (3 MFMAs) => ~fp32 accuracy.
// R6: single-pass softmax + F fixup table.
// R7(cfg): LDS group-XOR swizzle; qkv 128x64, pv BK=32 (proven, 369us).
// R9/R10: qkv standalone with LDS-bounce epilogue (coalesced stores).
//   R9 BUG: acc[2][2] -- needed FM=4 for BM=128/WM=2.  Fixed: acc[4][2].
//   V transpose now done ONCE in the qkv epilogue (transposed bounce
//   [64 d][136 pad] -> coalesced Vt[d][m] stores); k_pv reverted to the
//   R4-proven Vt+gl_lds16 form (avoids 16x re-transpose + LDS col-write
//   conflicts in the PV hot loop).
// ---------------------------------------------------------------------------

#define NB   2
#define SEQ  1024
#define CDIM 1024
#define NH   16
#define HD   64
#define ROWS (NB*SEQ)          // 2048
#define ATT_SCALE 0.125f       // 64^-0.5

typedef __attribute__((ext_vector_type(8))) short bf16x8;
typedef __attribute__((ext_vector_type(4))) float f32x4;

#define MFMA16(a,b,c) __builtin_amdgcn_mfma_f32_16x16x32_bf16((a),(b),(c),0,0,0)

static __device__ __forceinline__ unsigned short f2bf(float f) {
  uint32_t x = __builtin_bit_cast(uint32_t, f);
  return (unsigned short)((x + 0x7fffu + ((x >> 16) & 1u)) >> 16);   // RTN-even
}
static __device__ __forceinline__ float bf2f(unsigned short u) {
  uint32_t x = ((uint32_t)u) << 16;
  return __builtin_bit_cast(float, x);
}

// async global->LDS DMA, 16B/lane; lds dest = wave-uniform base + lane*16
static __device__ __forceinline__ void gl_lds16(const unsigned short* g,
                                                unsigned short* l) {
  __builtin_amdgcn_global_load_lds(
      (const __attribute__((address_space(1))) unsigned int*)g,
      (__attribute__((address_space(3))) unsigned int*)l,
      16, 0, 0);
}

// ---------------------------------------------------------------------------
// K0: fp32 -> bf16 hi/lo split for x and concatenated W = [Wq; Wkv; Wp]
// ---------------------------------------------------------------------------
__global__ __launch_bounds__(256) void k_convert(
    const float* __restrict__ x, const float* __restrict__ Wq,
    const float* __restrict__ Wkv, const float* __restrict__ Wp,
    unsigned short* __restrict__ Xhi, unsigned short* __restrict__ Xlo,
    unsigned short* __restrict__ Whi, unsigned short* __restrict__ Wlo)
{
  const int NX = ROWS * CDIM;
  const int NW = 4096 * CDIM;
  int i = blockIdx.x * 256 + threadIdx.x;
  if (i < NX) {
    float f = x[i];
    unsigned short h = f2bf(f);
    Xhi[i] = h; Xlo[i] = f2bf(f - bf2f(h));
  } else if (i < NX + NW) {
    int w = i - NX;
    int j = w >> 10, c = w & 1023;
    float f = (j < 1024) ? Wq[(size_t)j*1024 + c]
            : (j < 3072) ? Wkv[(size_t)(j-1024)*1024 + c]
                         : Wp[(size_t)(j-3072)*1024 + c];
    unsigned short h = f2bf(f);
    Whi[w] = h; Wlo[w] = f2bf(f - bf2f(h));
  }
}

// ---------------------------------------------------------------------------
// K1: QKV GEMM, standalone.  128x64 tile, 2x2 waves (FM=4, FN=2), BK=32,
// swizzled LDS.  Epilogue: LDS bounce -> coalesced uint4 stores.
//   seg 0/1 (Q/K): bounce [128 m][72 pad] -> Q/K[m][n] rows.
//   seg 2 (V):     bounce [64 d][136 pad] (transposed) -> Vt[d][m] rows.
// ---------------------------------------------------------------------------
__global__ __launch_bounds__(256) void k_gemm_qkv(
    const unsigned short* __restrict__ Xhi, const unsigned short* __restrict__ Xlo,
    const unsigned short* __restrict__ Whi, const unsigned short* __restrict__ Wlo,
    const float* __restrict__ bq, const float* __restrict__ bkv,
    unsigned short* __restrict__ Qhi, unsigned short* __restrict__ Qlo,
    unsigned short* __restrict__ Khi, unsigned short* __restrict__ Klo,
    unsigned short* __restrict__ Vthi, unsigned short* __restrict__ Vtlo)
{
  __shared__ unsigned short smem[12288];      // staging 24KB; bounce reuses it
  unsigned short* sAh = smem;                 // 128*32
  unsigned short* sAl = smem + 4096;
  unsigned short* sBh = smem + 8192;          // 64*32
  unsigned short* sBl = smem + 10240;
  const int tid = threadIdx.x, lane = tid & 63, wave = tid >> 6;
  const int wm = wave & 1, wn = wave >> 1;
  const int bn = blockIdx.x * 64, bm = blockIdx.y * 128;
  const int r = lane & 15, q = lane >> 4;
  const int crow = lane >> 2;
  const int cgsw = ((lane & 3) ^ ((crow >> 1) & 3)) * 8;
  const int qsw = (q ^ ((r >> 1) & 3)) * 8;

  f32x4 acc[4][2];
  #pragma unroll
  for (int i = 0; i < 4; i++)
    #pragma unroll
    for (int j = 0; j < 2; j++) {
      acc[i][j][0]=0.f; acc[i][j][1]=0.f; acc[i][j][2]=0.f; acc[i][j][3]=0.f;
    }

  for (int k0 = 0; k0 < CDIM; k0 += 32) {
    #pragma unroll
    for (int t = 0; t < 6; t++) {            // TOT=24 chunks / 4 waves
      int c = wave + t*4;
      const unsigned short* gb; unsigned short* sb; int rr, grow;
      if (c < 8)        { gb=Xhi; sb=sAh; rr=c;    grow=bm; }
      else if (c < 16)  { gb=Xlo; sb=sAl; rr=c-8;  grow=bm; }
      else if (c < 20)  { gb=Whi; sb=sBh; rr=c-16; grow=bn; }
      else              { gb=Wlo; sb=sBl; rr=c-20; grow=bn; }
      int row = rr*16 + crow;
      gl_lds16(gb + (size_t)(grow + row)*CDIM + k0 + cgsw, sb + rr*512);
    }
    __syncthreads();
    bf16x8 ah[4], al[4], bh[2], bl[2];
    #pragma unroll
    for (int i = 0; i < 4; i++) {
      int oa = (wm*64 + i*16 + r)*32 + qsw;
      ah[i] = *(const bf16x8*)(sAh + oa);
      al[i] = *(const bf16x8*)(sAl + oa);
    }
    #pragma unroll
    for (int j = 0; j < 2; j++) {
      int ob = (wn*32 + j*16 + r)*32 + qsw;
      bh[j] = *(const bf16x8*)(sBh + ob);
      bl[j] = *(const bf16x8*)(sBl + ob);
    }
    #pragma unroll
    for (int i = 0; i < 4; i++)
      #pragma unroll
      for (int j = 0; j < 2; j++) {
        acc[i][j] = MFMA16(ah[i], bh[j], acc[i][j]);
        acc[i][j] = MFMA16(ah[i], bl[j], acc[i][j]);
        acc[i][j] = MFMA16(al[i], bh[j], acc[i][j]);
      }
    __syncthreads();
  }

  // ---- epilogue: bias+scale, hi/lo split, LDS bounce, coalesced stores
  const int seg = bn >> 10;                       // 0=Q 1=K 2=V
  const float* bias = (seg == 0) ? (bq + bn) : (bkv + (bn - 1024));
  const float scl = (seg == 0) ? ATT_SCALE : 1.0f;
  float bj[2] = { bias[wn*32 + r], bias[wn*32 + 16 + r] };

  if (seg < 2) {
    unsigned short* dh = (seg == 0) ? Qhi : Khi;
    unsigned short* dl = (seg == 0) ? Qlo : Klo;
    const int ncol = bn & 1023;
    #pragma unroll
    for (int p = 0; p < 2; p++) {
      #pragma unroll
      for (int i = 0; i < 4; i++)
        #pragma unroll
        for (int j = 0; j < 2; j++)
          #pragma unroll
          for (int t = 0; t < 4; t++) {
            int m_l = wm*64 + i*16 + q*4 + t;
            int n_l = wn*32 + j*16 + r;
            float v2 = (acc[i][j][t] + bj[j]) * scl;
            unsigned short hv = f2bf(v2);
            unsigned short val = (p == 0) ? hv : f2bf(v2 - bf2f(hv));
            smem[m_l*72 + n_l] = val;
          }
      __syncthreads();
      unsigned short* dst = (p == 0) ? dh : dl;
      #pragma unroll
      for (int u = 0; u < 4; u++) {
        int s = u*256 + tid;
        int m_l = s >> 3, nseg = s & 7;
        uint4 vv = *(const uint4*)(smem + m_l*72 + nseg*8);
        *(uint4*)(dst + (size_t)(bm + m_l)*1024 + ncol + nseg*8) = vv;
      }
      __syncthreads();
    }
  } else {
    // V: transposed bounce [64 d][136 pad] -> Vt[((b*NH+h)*HD+d)*SEQ + m]
    const int h = (bn - 2048) >> 6;
    const int b = bm >> 10, mm = bm & 1023;
    const size_t vtb = ((size_t)((b*NH + h)*HD))*SEQ + mm;
    #pragma unroll
    for (int p = 0; p < 2; p++) {
      #pragma unroll
      for (int i = 0; i < 4; i++)
        #pragma unroll
        for (int j = 0; j < 2; j++)
          #pragma unroll
          for (int t = 0; t < 4; t++) {
            int m_l = wm*64 + i*16 + q*4 + t;
            int d_l = wn*32 + j*16 + r;
            float v2 = acc[i][j][t] + bj[j];
            unsigned short hv = f2bf(v2);
            unsigned short val = (p == 0) ? hv : f2bf(v2 - bf2f(hv));
            smem[d_l*136 + m_l] = val;
          }
      __syncthreads();
      unsigned short* dst = (p == 0) ? Vthi : Vtlo;
      #pragma unroll
      for (int u = 0; u < 4; u++) {
        int s = u*256 + tid;
        int d_l = s >> 4, mseg = s & 15;
        uint4 vv = *(const uint4*)(smem + d_l*136 + mseg*8);
        *(uint4*)(dst + vtb + (size_t)d_l*SEQ + mseg*8) = vv;
      }
      __syncthreads();
    }
  }
}

// ---------------------------------------------------------------------------
// Templated NT-GEMM core (split bf16, BK=32, wave grid WM x WN) -- k_gemm_out.
// ---------------------------------------------------------------------------
struct EpiOut {
  const float* bp; float* out;
  __device__ __forceinline__ void operator()(int m, int n, float v) const {
    out[(size_t)m*1024 + n] = v + bp[n];
  }
};

template <int BM, int BN, int WM, int WN, class Epi>
__device__ __forceinline__ void gemm_core(
    const unsigned short* __restrict__ Ahi, const unsigned short* __restrict__ Alo, int lda,
    const unsigned short* __restrict__ Bhi, const unsigned short* __restrict__ Blo, int ldb,
    int K, const Epi& epi)
{
  constexpr int WAVES = WM*WN;
  constexpr int FM = BM/(WM*16), FN = BN/(WN*16);
  constexpr int CA = BM/16, CB = BN/16;
  constexpr int TOT = 2*(CA+CB);
  __shared__ unsigned short sAh[BM*32], sAl[BM*32], sBh[BN*32], sBl[BN*32];
  const int tid  = threadIdx.x;
  const int lane = tid & 63, wave = tid >> 6;
  const int wm = wave % WM, wn = wave / WM;
  const int bn = blockIdx.x * BN, bm = blockIdx.y * BM;
  const int r = lane & 15, q = lane >> 4;
  const int crow = lane >> 2;
  const int cgsw = ((lane & 3) ^ ((crow >> 1) & 3)) * 8;   // swizzled src group
  const int qsw = (q ^ ((r >> 1) & 3)) * 8;                // swizzled read group

  f32x4 acc[FM][FN];
  #pragma unroll
  for (int i = 0; i < FM; i++)
    #pragma unroll
    for (int j = 0; j < FN; j++) {
      acc[i][j][0]=0.f; acc[i][j][1]=0.f; acc[i][j][2]=0.f; acc[i][j][3]=0.f;
    }

  for (int k0 = 0; k0 < K; k0 += 32) {
    #pragma unroll
    for (int t = 0; t < TOT/WAVES; t++) {
      int c = wave + t*WAVES;
      const unsigned short* gb; unsigned short* sb; int rr, grow, ld;
      if (c < CA)            { gb=Ahi; sb=sAh; rr=c;         grow=bm; ld=lda; }
      else if (c < 2*CA)     { gb=Alo; sb=sAl; rr=c-CA;      grow=bm; ld=lda; }
      else if (c < 2*CA+CB)  { gb=Bhi; sb=sBh; rr=c-2*CA;    grow=bn; ld=ldb; }
      else                   { gb=Blo; sb=sBl; rr=c-2*CA-CB; grow=bn; ld=ldb; }
      int row = rr*16 + crow;
      gl_lds16(gb + (size_t)(grow + row)*ld + k0 + cgsw, sb + rr*512);
    }
    __syncthreads();
    bf16x8 ah[FM], al[FM], bh[FN], bl[FN];
    #pragma unroll
    for (int i = 0; i < FM; i++) {
      int oa = (wm*(BM/WM) + i*16 + r)*32 + qsw;
      ah[i] = *(const bf16x8*)(sAh + oa);
      al[i] = *(const bf16x8*)(sAl + oa);
    }
    #pragma unroll
    for (int j = 0; j < FN; j++) {
      int ob = (wn*(BN/WN) + j*16 + r)*32 + qsw;
      bh[j] = *(const bf16x8*)(sBh + ob);
      bl[j] = *(const bf16x8*)(sBl + ob);
    }
    #pragma unroll
    for (int i = 0; i < FM; i++)
      #pragma unroll
      for (int j = 0; j < FN; j++) {
        acc[i][j] = MFMA16(ah[i], bh[j], acc[i][j]);
        acc[i][j] = MFMA16(ah[i], bl[j], acc[i][j]);
        acc[i][j] = MFMA16(al[i], bh[j], acc[i][j]);
      }
    __syncthreads();
  }
  #pragma unroll
  for (int i = 0; i < FM; i++)
    #pragma unroll
    for (int j = 0; j < FN; j++)
      #pragma unroll
      for (int t = 0; t < 4; t++)
        epi(bm + wm*(BM/WM) + i*16 + q*4 + t, bn + wn*(BN/WN) + j*16 + r, acc[i][j][t]);
}

__global__ __launch_bounds__(512) void k_gemm_out(
    const unsigned short* OAhi, const unsigned short* OAlo,
    const unsigned short* Wphi, const unsigned short* Wplo,
    const float* bp, float* out)
{
  EpiOut e{bp, out};
  gemm_core<128,64,4,2>(OAhi, OAlo, CDIM, Wphi, Wplo, CDIM, CDIM, e);
}

// ---------------------------------------------------------------------------
// K23: SINGLE-pass softmax -> u16 P (chunk-max quantized) + fixup table F.
// Block = 32 n-rows x one (b,h); 512 thr (8 waves).  K streamed ONCE in
// 128-m chunks (double-buffered, XOR-swizzled LDS).  mfma(K,Q): lane holds
// 4 m-values per nf.  Per chunk: row-wide max via shfl + LDS partials
// (redm double-buffered => 1 barrier/chunk); quantize vs running max;
// record m_c.  End: F[b,h,n,c] = exp(m_c - m_fin)/S;  prob = stored * F.
// ---------------------------------------------------------------------------
__global__ __launch_bounds__(512, 4) void k_logits_softmax(
    const unsigned short* __restrict__ Qhi, const unsigned short* __restrict__ Qlo,
    const unsigned short* __restrict__ Khi, const unsigned short* __restrict__ Klo,
    unsigned short* __restrict__ P, float* __restrict__ F)
{
  const int nt = blockIdx.x, h = blockIdx.y, b = blockIdx.z;
  const int n0 = nt*32;
  const int col0 = h*HD;
  __shared__ unsigned short sQ[2*32*64];       // [plane][32n x 64k] swizzled 8K
  __shared__ unsigned short sK[2][2*128*64];   // [buf][plane][128m x 64k] 64K
  __shared__ float redm[2][8][32];             // per-chunk wave partial max
  __shared__ float reds[8][32];                // final sum partials
  __shared__ float musd[32][8];                // m used per (row, chunk)
  const int tid = threadIdx.x, lane = tid & 63, wave = tid >> 6;
  const int r = lane & 15, q = lane >> 4;
  const int drow = lane >> 3, dseg = (lane & 7) ^ drow;   // DMA swizzle
  const int sw = r & 7;                                   // read swizzle
  const size_t qrow0 = (size_t)b*SEQ + n0;
  const size_t krow0 = (size_t)b*SEQ;

  auto stageK = [&](int c, int buf) {
    unsigned short* dst = sK[buf];
    #pragma unroll
    for (int u = 0; u < 4; u++) {
      int cc = wave*4 + u;                 // 0..31
      int p = cc >> 4, t = cc & 15;
      const unsigned short* g = p ? Klo : Khi;
      gl_lds16(g + (krow0 + (size_t)c*128 + t*8 + drow)*CDIM + col0 + dseg*8,
               dst + p*8192 + t*512);
    }
  };

  {   // stage Q (once) + K chunk 0
    int p = wave >> 2, t = wave & 3;
    const unsigned short* g = p ? Qlo : Qhi;
    gl_lds16(g + (qrow0 + t*8 + drow)*CDIM + col0 + dseg*8,
             sQ + p*2048 + t*512);
    stageK(0, 0);
  }
  __syncthreads();

  // Q fragments live in registers for the whole kernel
  bf16x8 qh[2][2], ql[2][2];
  #pragma unroll
  for (int nf = 0; nf < 2; nf++)
    #pragma unroll
    for (int ks = 0; ks < 2; ks++) {
      int phys = (nf*16 + r)*64 + (((ks*4 + q) ^ sw))*8;
      qh[nf][ks] = *(const bf16x8*)(sQ + phys);
      ql[nf][ks] = *(const bf16x8*)(sQ + 2048 + phys);
    }

  const int mb = wave*16;
  float m_run[2] = {-1e30f, -1e30f}, s_run[2] = {0.f, 0.f};
  const size_t pbase = ((size_t)(b*NH + h)*SEQ + n0)*SEQ;

  for (int c = 0; c < 8; c++) {
    if (c < 7) stageK(c+1, (c+1)&1);
    const unsigned short* cur = sK[c&1];
    bf16x8 kh[2], kl[2];
    #pragma unroll
    for (int ks = 0; ks < 2; ks++) {
      int phys = (mb + r)*64 + (((ks*4 + q) ^ sw))*8;
      kh[ks] = *(const bf16x8*)(cur + phys);
      kl[ks] = *(const bf16x8*)(cur + 8192 + phys);
    }
    f32x4 acc[2];
    #pragma unroll
    for (int nf = 0; nf < 2; nf++) {
      acc[nf][0]=0.f; acc[nf][1]=0.f; acc[nf][2]=0.f; acc[nf][3]=0.f;
      #pragma unroll
      for (int ks = 0; ks < 2; ks++) {
        acc[nf] = MFMA16(kh[ks], qh[nf][ks], acc[nf]);
        acc[nf] = MFMA16(kl[ks], qh[nf][ks], acc[nf]);
        acc[nf] = MFMA16(kh[ks], ql[nf][ks], acc[nf]);
      }
    }
    // wave-level row-chunk max (reduce over q groups)
    float wmax[2];
    #pragma unroll
    for (int nf = 0; nf < 2; nf++) {
      float v = fmaxf(fmaxf(acc[nf][0], acc[nf][1]), fmaxf(acc[nf][2], acc[nf][3]));
      v = fmaxf(v, __shfl_xor(v, 16));
      v = fmaxf(v, __shfl_xor(v, 32));
      wmax[nf] = v;
    }
    if (q == 0) { redm[c&1][wave][r] = wmax[0]; redm[c&1][wave][16+r] = wmax[1]; }
    __syncthreads();                       // 1 barrier/chunk
    #pragma unroll
    for (int nf = 0; nf < 2; nf++) {
      int row = nf*16 + r;
      float mc = redm[c&1][0][row];
      #pragma unroll
      for (int w2 = 1; w2 < 8; w2++) mc = fmaxf(mc, redm[c&1][w2][row]);
      float mnew = fmaxf(m_run[nf], mc);
      unsigned s0 = (unsigned)(__expf(acc[nf][0]-mnew)*65535.f + 0.5f);
      unsigned s1 = (unsigned)(__expf(acc[nf][1]-mnew)*65535.f + 0.5f);
      unsigned s2 = (unsigned)(__expf(acc[nf][2]-mnew)*65535.f + 0.5f);
      unsigned s3 = (unsigned)(__expf(acc[nf][3]-mnew)*65535.f + 0.5f);
      *(uint2*)(P + pbase + (size_t)row*SEQ + c*128 + mb + q*4) =
          make_uint2(s0 | (s1 << 16), s2 | (s3 << 16));
      s_run[nf] = s_run[nf]*__expf(m_run[nf]-mnew) + (float)(s0+s1+s2+s3);
      m_run[nf] = mnew;
      if (wave == 0 && q == 0) musd[row][c] = mnew;
    }
  }

  // ---- final sum reduction + F table
  #pragma unroll
  for (int nf = 0; nf < 2; nf++) {
    float s = s_run[nf];
    s += __shfl_xor(s, 16);
    s += __shfl_xor(s, 32);
    if (q == 0) reds[wave][nf*16 + r] = s;
  }
  __syncthreads();
  if (tid < 32) {
    int row = tid;
    float S = 0.f;
    #pragma unroll
    for (int w2 = 0; w2 < 8; w2++) S += reds[w2][row];
    float mfin = musd[row][7];
    float inv = 1.0f / S;
    size_t fb = ((size_t)(b*NH + h)*SEQ + n0 + row)*8;
    #pragma unroll
    for (int c = 0; c < 8; c++)
      F[fb + c] = __expf(musd[row][c] - mfin) * inv;
  }
}

// ---------------------------------------------------------------------------
// K_attn: dequant-transpose P[b][h][n][m] u16 * F -> attn[b][n][m][h] f32.
// One thread per (b,n,m): 16 coalesced u16 loads + 16 L2-hot F loads,
// 4 contiguous float4 stores.
// ---------------------------------------------------------------------------
__global__ __launch_bounds__(256) void k_attn_write(
    const unsigned short* __restrict__ P, const float* __restrict__ F,
    float* __restrict__ attn)
{
  int T = blockIdx.x*256 + threadIdx.x;
  int b = T >> 20, rem = T & 1048575;
  int n = rem >> 10, m = rem & 1023;
  int c = m >> 7;
  const size_t pb = ((size_t)(b*NH)*SEQ + n)*SEQ + m;
  const size_t fb = ((size_t)(b*NH)*SEQ + n)*8 + c;
  float v[16];
  #pragma unroll
  for (int h = 0; h < 16; h++)
    v[h] = (float)P[pb + (size_t)h*SEQ*SEQ] * F[fb + (size_t)h*SEQ*8];
  size_t ob = ((size_t)(b*SEQ + n)*SEQ + m)*16;
  #pragma unroll
  for (int g = 0; g < 4; g++)
    *(float4*)(attn + ob + g*4) = make_float4(v[g*4], v[g*4+1], v[g*4+2], v[g*4+3]);
}

// ---------------------------------------------------------------------------
// K4: PV gemm per (b,h):  OA[n][d] = sum_c F[n][c] * sum_{m in c} P_u16 * V
// 64n x 64d per block (512 blocks); exact byte-split planes of stored u16;
// per-chunk fold accF += acc * F.  R4-proven form: Vt staged via gl_lds16.
// ---------------------------------------------------------------------------
__global__ __launch_bounds__(256) void k_pv(
    const unsigned short* __restrict__ P, const float* __restrict__ F,
    const unsigned short* __restrict__ Vthi, const unsigned short* __restrict__ Vtlo,
    unsigned short* __restrict__ OAhi, unsigned short* __restrict__ OAlo)
{
  int nt = blockIdx.x, h = blockIdx.y, b = blockIdx.z;
  int n0 = nt * 64;
  __shared__ unsigned short sPa[64*32], sPb[64*32], sVh[64*32], sVl[64*32];
  const int tid = threadIdx.x, lane = tid & 63, wave = tid >> 6;
  const int wm = wave & 1, wn = wave >> 1;
  const int r = lane & 15, q = lane >> 4;
  const int crow = lane >> 2;
  const int cgsw = ((lane & 3) ^ ((crow >> 1) & 3)) * 8;   // swizzled src group
  const int qsw = (q ^ ((r >> 1) & 3)) * 8;                // swizzled read group
  const size_t pbase = ((size_t)(b*NH + h))*SEQ*SEQ;
  const size_t vbase = ((size_t)(b*NH + h))*HD*SEQ;
  const size_t fbase = ((size_t)(b*NH + h))*SEQ*8;

  f32x4 acc[2][2], accF[2][2];
  #pragma unroll
  for (int i = 0; i < 2; i++)
    #pragma unroll
    for (int j = 0; j < 2; j++) {
      acc[i][j][0]=0.f; acc[i][j][1]=0.f; acc[i][j][2]=0.f; acc[i][j][3]=0.f;
      accF[i][j][0]=0.f; accF[i][j][1]=0.f; accF[i][j][2]=0.f; accF[i][j][3]=0.f;
    }

  for (int k0 = 0; k0 < SEQ; k0 += 32) {
    #pragma unroll
    for (int t = 0; t < 2; t++) {
      int c = wave + t*4;
      const unsigned short* gb = (c < 4) ? Vthi : Vtlo;
      unsigned short* sb = (c < 4) ? (unsigned short*)sVh : (unsigned short*)sVl;
      int rr = c & 3;
      int row = rr*16 + crow;
      gl_lds16(gb + vbase + (size_t)row*SEQ + k0 + cgsw, sb + rr*512);
    }
    {
      int row = tid >> 2, g = tid & 3, ch = g * 8;
      int gp = (g ^ ((row >> 1) & 3)) * 8;                 // swizzled LDS slot
      uint4 v = *(const uint4*)(P + pbase + (size_t)(n0 + row)*SEQ + k0 + ch);
      unsigned int wds[4] = {v.x, v.y, v.z, v.w};
      unsigned int pa[4], pb4[4];
      #pragma unroll
      for (int e = 0; e < 4; e++) {
        unsigned int lo16 = wds[e] & 0xFFFFu;
        unsigned int hi16 = wds[e] >> 16;
        unsigned int a0 = __builtin_bit_cast(uint32_t, (float)(lo16 & 0xFF00u)) >> 16;
        unsigned int b0 = __builtin_bit_cast(uint32_t, (float)(lo16 & 0x00FFu)) >> 16;
        unsigned int a1 = __builtin_bit_cast(uint32_t, (float)(hi16 & 0xFF00u)) >> 16;
        unsigned int b1 = __builtin_bit_cast(uint32_t, (float)(hi16 & 0x00FFu)) >> 16;
        pa[e]  = a0 | (a1 << 16);
        pb4[e] = b0 | (b1 << 16);
      }
      *(uint4*)(sPa + row*32 + gp) = make_uint4(pa[0],pa[1],pa[2],pa[3]);
      *(uint4*)(sPb + row*32 + gp) = make_uint4(pb4[0],pb4[1],pb4[2],pb4[3]);
    }
    __syncthreads();
    bf16x8 pa[2], pb2[2], vh[2], vl[2];
    #pragma unroll
    for (int i = 0; i < 2; i++) {
      int off = (wm*32 + i*16 + r)*32 + qsw;
      pa[i]  = *(const bf16x8*)(sPa + off);
      pb2[i] = *(const bf16x8*)(sPb + off);
    }
    #pragma unroll
    for (int j = 0; j < 2; j++) {
      int off = (wn*32 + j*16 + r)*32 + qsw;
      vh[j] = *(const bf16x8*)(sVh + off);
      vl[j] = *(const bf16x8*)(sVl + off);
    }
    #pragma unroll
    for (int i = 0; i < 2; i++)
      #pragma unroll
      for (int j = 0; j < 2; j++) {
        acc[i][j] = MFMA16(pa[i],  vh[j], acc[i][j]);
        acc[i][j] = MFMA16(pb2[i], vh[j], acc[i][j]);
        acc[i][j] = MFMA16(pa[i],  vl[j], acc[i][j]);
      }
    if ((k0 & 127) == 96) {                // end of 128-m chunk: fold with F
      int c = k0 >> 7;
      #pragma unroll
      for (int i = 0; i < 2; i++)
        #pragma unroll
        for (int t = 0; t < 4; t++) {
          int nn = n0 + wm*32 + i*16 + q*4 + t;
          float Fv = F[fbase + (size_t)nn*8 + c];
          #pragma unroll
          for (int j = 0; j < 2; j++) {
            accF[i][j][t] += acc[i][j][t] * Fv;
            acc[i][j][t] = 0.f;
          }
        }
    }
    __syncthreads();
  }
  #pragma unroll
  for (int i = 0; i < 2; i++)
    #pragma unroll
    for (int t = 0; t < 4; t++) {
      int nn = n0 + wm*32 + i*16 + q*4 + t;
      #pragma unroll
      for (int j = 0; j < 2; j++) {
        int d = wn*32 + j*16 + r;
        float val = accF[i][j][t];
        size_t o = (size_t)(b*SEQ + nn)*CDIM + h*HD + d;
        unsigned short hb = f2bf(val);
        OAhi[o] = hb; OAlo[o] = f2bf(val - bf2f(hb));
      }
    }
}

// ---------------------------------------------------------------------------
extern "C" void kernel_launch(void* const* d_in, const int* in_sizes, int n_in,
                              void* d_out, int out_size, void* d_ws, size_t ws_size,
                              hipStream_t stream)
{
  const float* x   = (const float*)d_in[0];
  const float* Wq  = (const float*)d_in[1];
  const float* bq  = (const float*)d_in[2];
  const float* Wkv = (const float*)d_in[3];
  const float* bkv = (const float*)d_in[4];
  const float* Wp  = (const float*)d_in[5];
  const float* bp  = (const float*)d_in[6];

  float* out  = (float*)d_out;
  float* attn = out + (size_t)ROWS*CDIM;

  char* w = (char*)d_ws;
  unsigned short* Xhi  = (unsigned short*)w; w += (size_t)ROWS*CDIM*2;
  unsigned short* Xlo  = (unsigned short*)w; w += (size_t)ROWS*CDIM*2;
  unsigned short* Whi  = (unsigned short*)w; w += (size_t)4096*CDIM*2;
  unsigned short* Wlo  = (unsigned short*)w; w += (size_t)4096*CDIM*2;
  unsigned short* Qhi  = (unsigned short*)w; w += (size_t)ROWS*CDIM*2;
  unsigned short* Qlo  = (unsigned short*)w; w += (size_t)ROWS*CDIM*2;
  unsigned short* Khi  = (unsigned short*)w; w += (size_t)ROWS*CDIM*2;
  unsigned short* Klo  = (unsigned short*)w; w += (size_t)ROWS*CDIM*2;
  unsigned short* Vthi = (unsigned short*)w; w += (size_t)NB*NH*HD*SEQ*2;
  unsigned short* Vtlo = (unsigned short*)w; w += (size_t)NB*NH*HD*SEQ*2;
  unsigned short* OAhi = (unsigned short*)w; w += (size_t)ROWS*CDIM*2;
  unsigned short* OAlo = (unsigned short*)w; w += (size_t)ROWS*CDIM*2;
  unsigned short* P    = (unsigned short*)w; w += (size_t)NB*NH*SEQ*SEQ*2;
  float*          Ftab = (float*)w;          w += (size_t)NB*NH*SEQ*8*4;

  k_convert<<<dim3((ROWS*CDIM + 4096*CDIM)/256), 256, 0, stream>>>(
      x, Wq, Wkv, Wp, Xhi, Xlo, Whi, Wlo);

  k_gemm_qkv<<<dim3(3072/64, 2048/128), 256, 0, stream>>>(
      Xhi, Xlo, Whi, Wlo, bq, bkv, Qhi, Qlo, Khi, Klo, Vthi, Vtlo);

  k_logits_softmax<<<dim3(SEQ/32, NH, NB), 512, 0, stream>>>(
      Qhi, Qlo, Khi, Klo, P, Ftab);

  k_pv<<<dim3(SEQ/64, NH, NB), 256, 0, stream>>>(P, Ftab, Vthi, Vtlo, OAhi, OAlo);

  k_gemm_out<<<dim3(1024/64, 2048/128), 512, 0, stream>>>(
      OAhi, OAlo, Whi + (size_t)3072*CDIM, Wlo + (size_t)3072*CDIM, bp, out);

  k_attn_write<<<dim3((NB*SEQ*SEQ)/256), 256, 0, stream>>>(P, Ftab, attn);
}

// Round 8
// 350.183 us; speedup vs baseline: 1.0751x; 1.0271x over previous
//
#include <hip/hip_runtime.h>
#include <hip/hip_bf16.h>
#include <stdint.h>

// ---------------------------------------------------------------------------
// MultiHeadAttention on MI355X (gfx950).
// b=2, n=1024, DIM=1024, H=16, dh=64.  Outputs: out (2M f32) ++ attn (33.5M f32).
// GEMMs: bf16 MFMA 16x16x32, hi/lo split (3 MFMAs) => ~fp32 accuracy.
// R6: single-pass softmax + F fixup table.
// R7(cfg): LDS group-XOR swizzle; qkv 128x64, pv BK=32 (proven).
// R10: qkv standalone, LDS-bounce epilogue, V transposed once in epilogue
//      (359.7us, absmax 2.44e-4).
// R11: (a) k_convert vectorized x4 (float4 in, uint2 hi/lo out) -- was
//      scalar 1 elem/thread;  (b) XCD-chunked blockIdx swizzle on
//      k_logits_softmax (each XCD then holds 4 K-head-panels = 2MB < 4MB L2
//      vs ~16 panels unswizzled) and k_pv (same structure on Vt panels).
//      qkv/out NOT swizzled (shared panels exceed L2 either way).
// ---------------------------------------------------------------------------

#define NB   2
#define SEQ  1024
#define CDIM 1024
#define NH   16
#define HD   64
#define ROWS (NB*SEQ)          // 2048
#define ATT_SCALE 0.125f       // 64^-0.5

typedef __attribute__((ext_vector_type(8))) short bf16x8;
typedef __attribute__((ext_vector_type(4))) float f32x4;

#define MFMA16(a,b,c) __builtin_amdgcn_mfma_f32_16x16x32_bf16((a),(b),(c),0,0,0)

static __device__ __forceinline__ unsigned short f2bf(float f) {
  uint32_t x = __builtin_bit_cast(uint32_t, f);
  return (unsigned short)((x + 0x7fffu + ((x >> 16) & 1u)) >> 16);   // RTN-even
}
static __device__ __forceinline__ float bf2f(unsigned short u) {
  uint32_t x = ((uint32_t)u) << 16;
  return __builtin_bit_cast(float, x);
}

// async global->LDS DMA, 16B/lane; lds dest = wave-uniform base + lane*16
static __device__ __forceinline__ void gl_lds16(const unsigned short* g,
                                                unsigned short* l) {
  __builtin_amdgcn_global_load_lds(
      (const __attribute__((address_space(1))) unsigned int*)g,
      (__attribute__((address_space(3))) unsigned int*)l,
      16, 0, 0);
}

// ---------------------------------------------------------------------------
// K0: fp32 -> bf16 hi/lo split for x and concatenated W = [Wq; Wkv; Wp]
// Vectorized: 4 f32 per thread, packed uint2 stores per plane.
// ---------------------------------------------------------------------------
__global__ __launch_bounds__(256) void k_convert(
    const float* __restrict__ x, const float* __restrict__ Wq,
    const float* __restrict__ Wkv, const float* __restrict__ Wp,
    unsigned short* __restrict__ Xhi, unsigned short* __restrict__ Xlo,
    unsigned short* __restrict__ Whi, unsigned short* __restrict__ Wlo)
{
  const int NX4 = ROWS*CDIM/4;       // 524288
  const int NW4 = 4096*CDIM/4;       // 1048576
  int i = blockIdx.x*256 + threadIdx.x;
  float4 f;
  unsigned short* dh;
  unsigned short* dl;
  size_t o4;
  if (i < NX4) {
    f = ((const float4*)x)[i];
    dh = Xhi; dl = Xlo; o4 = (size_t)i*4;
  } else if (i < NX4 + NW4) {
    int w4 = i - NX4;
    int j = w4 >> 8;                 // row (w4*4 / 1024)
    int c4 = w4 & 255;               // col/4
    const float* ws = (j < 1024) ? Wq + (size_t)j*1024
                    : (j < 3072) ? Wkv + (size_t)(j-1024)*1024
                                 : Wp + (size_t)(j-3072)*1024;
    f = ((const float4*)ws)[c4];
    dh = Whi; dl = Wlo; o4 = (size_t)w4*4;
  } else return;
  float fv[4] = {f.x, f.y, f.z, f.w};
  unsigned int hp[2], lp[2];
  #pragma unroll
  for (int e = 0; e < 2; e++) {
    unsigned short h0 = f2bf(fv[e*2]),   l0 = f2bf(fv[e*2]   - bf2f(h0));
    unsigned short h1 = f2bf(fv[e*2+1]), l1 = f2bf(fv[e*2+1] - bf2f(h1));
    hp[e] = (unsigned)h0 | ((unsigned)h1 << 16);
    lp[e] = (unsigned)l0 | ((unsigned)l1 << 16);
  }
  *(uint2*)(dh + o4) = make_uint2(hp[0], hp[1]);
  *(uint2*)(dl + o4) = make_uint2(lp[0], lp[1]);
}

// ---------------------------------------------------------------------------
// K1: QKV GEMM, standalone.  128x64 tile, 2x2 waves (FM=4, FN=2), BK=32,
// swizzled LDS.  Epilogue: LDS bounce -> coalesced uint4 stores.
//   seg 0/1 (Q/K): bounce [128 m][72 pad] -> Q/K[m][n] rows.
//   seg 2 (V):     bounce [64 d][136 pad] (transposed) -> Vt[d][m] rows.
// ---------------------------------------------------------------------------
__global__ __launch_bounds__(256) void k_gemm_qkv(
    const unsigned short* __restrict__ Xhi, const unsigned short* __restrict__ Xlo,
    const unsigned short* __restrict__ Whi, const unsigned short* __restrict__ Wlo,
    const float* __restrict__ bq, const float* __restrict__ bkv,
    unsigned short* __restrict__ Qhi, unsigned short* __restrict__ Qlo,
    unsigned short* __restrict__ Khi, unsigned short* __restrict__ Klo,
    unsigned short* __restrict__ Vthi, unsigned short* __restrict__ Vtlo)
{
  __shared__ unsigned short smem[12288];      // staging 24KB; bounce reuses it
  unsigned short* sAh = smem;                 // 128*32
  unsigned short* sAl = smem + 4096;
  unsigned short* sBh = smem + 8192;          // 64*32
  unsigned short* sBl = smem + 10240;
  const int tid = threadIdx.x, lane = tid & 63, wave = tid >> 6;
  const int wm = wave & 1, wn = wave >> 1;
  const int bn = blockIdx.x * 64, bm = blockIdx.y * 128;
  const int r = lane & 15, q = lane >> 4;
  const int crow = lane >> 2;
  const int cgsw = ((lane & 3) ^ ((crow >> 1) & 3)) * 8;
  const int qsw = (q ^ ((r >> 1) & 3)) * 8;

  f32x4 acc[4][2];
  #pragma unroll
  for (int i = 0; i < 4; i++)
    #pragma unroll
    for (int j = 0; j < 2; j++) {
      acc[i][j][0]=0.f; acc[i][j][1]=0.f; acc[i][j][2]=0.f; acc[i][j][3]=0.f;
    }

  for (int k0 = 0; k0 < CDIM; k0 += 32) {
    #pragma unroll
    for (int t = 0; t < 6; t++) {            // TOT=24 chunks / 4 waves
      int c = wave + t*4;
      const unsigned short* gb; unsigned short* sb; int rr, grow;
      if (c < 8)        { gb=Xhi; sb=sAh; rr=c;    grow=bm; }
      else if (c < 16)  { gb=Xlo; sb=sAl; rr=c-8;  grow=bm; }
      else if (c < 20)  { gb=Whi; sb=sBh; rr=c-16; grow=bn; }
      else              { gb=Wlo; sb=sBl; rr=c-20; grow=bn; }
      int row = rr*16 + crow;
      gl_lds16(gb + (size_t)(grow + row)*CDIM + k0 + cgsw, sb + rr*512);
    }
    __syncthreads();
    bf16x8 ah[4], al[4], bh[2], bl[2];
    #pragma unroll
    for (int i = 0; i < 4; i++) {
      int oa = (wm*64 + i*16 + r)*32 + qsw;
      ah[i] = *(const bf16x8*)(sAh + oa);
      al[i] = *(const bf16x8*)(sAl + oa);
    }
    #pragma unroll
    for (int j = 0; j < 2; j++) {
      int ob = (wn*32 + j*16 + r)*32 + qsw;
      bh[j] = *(const bf16x8*)(sBh + ob);
      bl[j] = *(const bf16x8*)(sBl + ob);
    }
    #pragma unroll
    for (int i = 0; i < 4; i++)
      #pragma unroll
      for (int j = 0; j < 2; j++) {
        acc[i][j] = MFMA16(ah[i], bh[j], acc[i][j]);
        acc[i][j] = MFMA16(ah[i], bl[j], acc[i][j]);
        acc[i][j] = MFMA16(al[i], bh[j], acc[i][j]);
      }
    __syncthreads();
  }

  // ---- epilogue: bias+scale, hi/lo split, LDS bounce, coalesced stores
  const int seg = bn >> 10;                       // 0=Q 1=K 2=V
  const float* bias = (seg == 0) ? (bq + bn) : (bkv + (bn - 1024));
  const float scl = (seg == 0) ? ATT_SCALE : 1.0f;
  float bj[2] = { bias[wn*32 + r], bias[wn*32 + 16 + r] };

  if (seg < 2) {
    unsigned short* dh = (seg == 0) ? Qhi : Khi;
    unsigned short* dl = (seg == 0) ? Qlo : Klo;
    const int ncol = bn & 1023;
    #pragma unroll
    for (int p = 0; p < 2; p++) {
      #pragma unroll
      for (int i = 0; i < 4; i++)
        #pragma unroll
        for (int j = 0; j < 2; j++)
          #pragma unroll
          for (int t = 0; t < 4; t++) {
            int m_l = wm*64 + i*16 + q*4 + t;
            int n_l = wn*32 + j*16 + r;
            float v2 = (acc[i][j][t] + bj[j]) * scl;
            unsigned short hv = f2bf(v2);
            unsigned short val = (p == 0) ? hv : f2bf(v2 - bf2f(hv));
            smem[m_l*72 + n_l] = val;
          }
      __syncthreads();
      unsigned short* dst = (p == 0) ? dh : dl;
      #pragma unroll
      for (int u = 0; u < 4; u++) {
        int s = u*256 + tid;
        int m_l = s >> 3, nseg = s & 7;
        uint4 vv = *(const uint4*)(smem + m_l*72 + nseg*8);
        *(uint4*)(dst + (size_t)(bm + m_l)*1024 + ncol + nseg*8) = vv;
      }
      __syncthreads();
    }
  } else {
    // V: transposed bounce [64 d][136 pad] -> Vt[((b*NH+h)*HD+d)*SEQ + m]
    const int h = (bn - 2048) >> 6;
    const int b = bm >> 10, mm = bm & 1023;
    const size_t vtb = ((size_t)((b*NH + h)*HD))*SEQ + mm;
    #pragma unroll
    for (int p = 0; p < 2; p++) {
      #pragma unroll
      for (int i = 0; i < 4; i++)
        #pragma unroll
        for (int j = 0; j < 2; j++)
          #pragma unroll
          for (int t = 0; t < 4; t++) {
            int m_l = wm*64 + i*16 + q*4 + t;
            int d_l = wn*32 + j*16 + r;
            float v2 = acc[i][j][t] + bj[j];
            unsigned short hv = f2bf(v2);
            unsigned short val = (p == 0) ? hv : f2bf(v2 - bf2f(hv));
            smem[d_l*136 + m_l] = val;
          }
      __syncthreads();
      unsigned short* dst = (p == 0) ? Vthi : Vtlo;
      #pragma unroll
      for (int u = 0; u < 4; u++) {
        int s = u*256 + tid;
        int d_l = s >> 4, mseg = s & 15;
        uint4 vv = *(const uint4*)(smem + d_l*136 + mseg*8);
        *(uint4*)(dst + vtb + (size_t)d_l*SEQ + mseg*8) = vv;
      }
      __syncthreads();
    }
  }
}

// ---------------------------------------------------------------------------
// Templated NT-GEMM core (split bf16, BK=32, wave grid WM x WN) -- k_gemm_out.
// ---------------------------------------------------------------------------
struct EpiOut {
  const float* bp; float* out;
  __device__ __forceinline__ void operator()(int m, int n, float v) const {
    out[(size_t)m*1024 + n] = v + bp[n];
  }
};

template <int BM, int BN, int WM, int WN, class Epi>
__device__ __forceinline__ void gemm_core(
    const unsigned short* __restrict__ Ahi, const unsigned short* __restrict__ Alo, int lda,
    const unsigned short* __restrict__ Bhi, const unsigned short* __restrict__ Blo, int ldb,
    int K, const Epi& epi)
{
  constexpr int WAVES = WM*WN;
  constexpr int FM = BM/(WM*16), FN = BN/(WN*16);
  constexpr int CA = BM/16, CB = BN/16;
  constexpr int TOT = 2*(CA+CB);
  __shared__ unsigned short sAh[BM*32], sAl[BM*32], sBh[BN*32], sBl[BN*32];
  const int tid  = threadIdx.x;
  const int lane = tid & 63, wave = tid >> 6;
  const int wm = wave % WM, wn = wave / WM;
  const int bn = blockIdx.x * BN, bm = blockIdx.y * BM;
  const int r = lane & 15, q = lane >> 4;
  const int crow = lane >> 2;
  const int cgsw = ((lane & 3) ^ ((crow >> 1) & 3)) * 8;   // swizzled src group
  const int qsw = (q ^ ((r >> 1) & 3)) * 8;                // swizzled read group

  f32x4 acc[FM][FN];
  #pragma unroll
  for (int i = 0; i < FM; i++)
    #pragma unroll
    for (int j = 0; j < FN; j++) {
      acc[i][j][0]=0.f; acc[i][j][1]=0.f; acc[i][j][2]=0.f; acc[i][j][3]=0.f;
    }

  for (int k0 = 0; k0 < K; k0 += 32) {
    #pragma unroll
    for (int t = 0; t < TOT/WAVES; t++) {
      int c = wave + t*WAVES;
      const unsigned short* gb; unsigned short* sb; int rr, grow, ld;
      if (c < CA)            { gb=Ahi; sb=sAh; rr=c;         grow=bm; ld=lda; }
      else if (c < 2*CA)     { gb=Alo; sb=sAl; rr=c-CA;      grow=bm; ld=lda; }
      else if (c < 2*CA+CB)  { gb=Bhi; sb=sBh; rr=c-2*CA;    grow=bn; ld=ldb; }
      else                   { gb=Blo; sb=sBl; rr=c-2*CA-CB; grow=bn; ld=ldb; }
      int row = rr*16 + crow;
      gl_lds16(gb + (size_t)(grow + row)*ld + k0 + cgsw, sb + rr*512);
    }
    __syncthreads();
    bf16x8 ah[FM], al[FM], bh[FN], bl[FN];
    #pragma unroll
    for (int i = 0; i < FM; i++) {
      int oa = (wm*(BM/WM) + i*16 + r)*32 + qsw;
      ah[i] = *(const bf16x8*)(sAh + oa);
      al[i] = *(const bf16x8*)(sAl + oa);
    }
    #pragma unroll
    for (int j = 0; j < FN; j++) {
      int ob = (wn*(BN/WN) + j*16 + r)*32 + qsw;
      bh[j] = *(const bf16x8*)(sBh + ob);
      bl[j] = *(const bf16x8*)(sBl + ob);
    }
    #pragma unroll
    for (int i = 0; i < FM; i++)
      #pragma unroll
      for (int j = 0; j < FN; j++) {
        acc[i][j] = MFMA16(ah[i], bh[j], acc[i][j]);
        acc[i][j] = MFMA16(ah[i], bl[j], acc[i][j]);
        acc[i][j] = MFMA16(al[i], bh[j], acc[i][j]);
      }
    __syncthreads();
  }
  #pragma unroll
  for (int i = 0; i < FM; i++)
    #pragma unroll
    for (int j = 0; j < FN; j++)
      #pragma unroll
      for (int t = 0; t < 4; t++)
        epi(bm + wm*(BM/WM) + i*16 + q*4 + t, bn + wn*(BN/WN) + j*16 + r, acc[i][j][t]);
}

__global__ __launch_bounds__(512) void k_gemm_out(
    const unsigned short* OAhi, const unsigned short* OAlo,
    const unsigned short* Wphi, const unsigned short* Wplo,
    const float* bp, float* out)
{
  EpiOut e{bp, out};
  gemm_core<128,64,4,2>(OAhi, OAlo, CDIM, Wphi, Wplo, CDIM, CDIM, e);
}

// ---------------------------------------------------------------------------
// K23: SINGLE-pass softmax -> u16 P (chunk-max quantized) + fixup table F.
// Block = 32 n-rows x one (b,h); 512 thr (8 waves).  K streamed ONCE in
// 128-m chunks (double-buffered, XOR-swizzled LDS).  XCD-chunked block
// swizzle: each XCD serves 4 contiguous (b,h) K-panels (2MB, L2-resident).
// ---------------------------------------------------------------------------
__global__ __launch_bounds__(512, 4) void k_logits_softmax(
    const unsigned short* __restrict__ Qhi, const unsigned short* __restrict__ Qlo,
    const unsigned short* __restrict__ Khi, const unsigned short* __restrict__ Klo,
    unsigned short* __restrict__ P, float* __restrict__ F)
{
  int id = blockIdx.x + 32*(blockIdx.y + 16*blockIdx.z);   // 1024 blocks
  id = (id & 7)*128 + (id >> 3);                           // XCD chunked
  const int nt = id & 31, h = (id >> 5) & 15, b = id >> 9;
  const int n0 = nt*32;
  const int col0 = h*HD;
  __shared__ unsigned short sQ[2*32*64];       // [plane][32n x 64k] swizzled 8K
  __shared__ unsigned short sK[2][2*8192];     // [buf][plane][128m x 64k] 64K
  __shared__ float redm[2][8][32];             // per-chunk wave partial max
  __shared__ float reds[8][32];                // final sum partials
  __shared__ float musd[32][8];                // m used per (row, chunk)
  const int tid = threadIdx.x, lane = tid & 63, wave = tid >> 6;
  const int r = lane & 15, q = lane >> 4;
  const int drow = lane >> 3, dseg = (lane & 7) ^ drow;   // DMA swizzle
  const int sw = r & 7;                                   // read swizzle
  const size_t qrow0 = (size_t)b*SEQ + n0;
  const size_t krow0 = (size_t)b*SEQ;

  auto stageK = [&](int c, int buf) {
    unsigned short* dst = sK[buf];
    #pragma unroll
    for (int u = 0; u < 4; u++) {
      int cc = wave*4 + u;                 // 0..31
      int p = cc >> 4, t = cc & 15;
      const unsigned short* g = p ? Klo : Khi;
      gl_lds16(g + (krow0 + (size_t)c*128 + t*8 + drow)*CDIM + col0 + dseg*8,
               dst + p*8192 + t*512);
    }
  };

  {   // stage Q (once) + K chunk 0
    int p = wave >> 2, t = wave & 3;
    const unsigned short* g = p ? Qlo : Qhi;
    gl_lds16(g + (qrow0 + t*8 + drow)*CDIM + col0 + dseg*8,
             sQ + p*2048 + t*512);
    stageK(0, 0);
  }
  __syncthreads();

  // Q fragments live in registers for the whole kernel
  bf16x8 qh[2][2], ql[2][2];
  #pragma unroll
  for (int nf = 0; nf < 2; nf++)
    #pragma unroll
    for (int ks = 0; ks < 2; ks++) {
      int phys = (nf*16 + r)*64 + (((ks*4 + q) ^ sw))*8;
      qh[nf][ks] = *(const bf16x8*)(sQ + phys);
      ql[nf][ks] = *(const bf16x8*)(sQ + 2048 + phys);
    }

  const int mb = wave*16;
  float m_run[2] = {-1e30f, -1e30f}, s_run[2] = {0.f, 0.f};
  const size_t pbase = ((size_t)(b*NH + h)*SEQ + n0)*SEQ;

  for (int c = 0; c < 8; c++) {
    if (c < 7) stageK(c+1, (c+1)&1);
    const unsigned short* cur = sK[c&1];
    bf16x8 kh[2], kl[2];
    #pragma unroll
    for (int ks = 0; ks < 2; ks++) {
      int phys = (mb + r)*64 + (((ks*4 + q) ^ sw))*8;
      kh[ks] = *(const bf16x8*)(cur + phys);
      kl[ks] = *(const bf16x8*)(cur + 8192 + phys);
    }
    f32x4 acc[2];
    #pragma unroll
    for (int nf = 0; nf < 2; nf++) {
      acc[nf][0]=0.f; acc[nf][1]=0.f; acc[nf][2]=0.f; acc[nf][3]=0.f;
      #pragma unroll
      for (int ks = 0; ks < 2; ks++) {
        acc[nf] = MFMA16(kh[ks], qh[nf][ks], acc[nf]);
        acc[nf] = MFMA16(kl[ks], qh[nf][ks], acc[nf]);
        acc[nf] = MFMA16(kh[ks], ql[nf][ks], acc[nf]);
      }
    }
    // wave-level row-chunk max (reduce over q groups)
    float wmax[2];
    #pragma unroll
    for (int nf = 0; nf < 2; nf++) {
      float v = fmaxf(fmaxf(acc[nf][0], acc[nf][1]), fmaxf(acc[nf][2], acc[nf][3]));
      v = fmaxf(v, __shfl_xor(v, 16));
      v = fmaxf(v, __shfl_xor(v, 32));
      wmax[nf] = v;
    }
    if (q == 0) { redm[c&1][wave][r] = wmax[0]; redm[c&1][wave][16+r] = wmax[1]; }
    __syncthreads();                       // 1 barrier/chunk
    #pragma unroll
    for (int nf = 0; nf < 2; nf++) {
      int row = nf*16 + r;
      float mc = redm[c&1][0][row];
      #pragma unroll
      for (int w2 = 1; w2 < 8; w2++) mc = fmaxf(mc, redm[c&1][w2][row]);
      float mnew = fmaxf(m_run[nf], mc);
      unsigned s0 = (unsigned)(__expf(acc[nf][0]-mnew)*65535.f + 0.5f);
      unsigned s1 = (unsigned)(__expf(acc[nf][1]-mnew)*65535.f + 0.5f);
      unsigned s2 = (unsigned)(__expf(acc[nf][2]-mnew)*65535.f + 0.5f);
      unsigned s3 = (unsigned)(__expf(acc[nf][3]-mnew)*65535.f + 0.5f);
      *(uint2*)(P + pbase + (size_t)row*SEQ + c*128 + mb + q*4) =
          make_uint2(s0 | (s1 << 16), s2 | (s3 << 16));
      s_run[nf] = s_run[nf]*__expf(m_run[nf]-mnew) + (float)(s0+s1+s2+s3);
      m_run[nf] = mnew;
      if (wave == 0 && q == 0) musd[row][c] = mnew;
    }
  }

  // ---- final sum reduction + F table
  #pragma unroll
  for (int nf = 0; nf < 2; nf++) {
    float s = s_run[nf];
    s += __shfl_xor(s, 16);
    s += __shfl_xor(s, 32);
    if (q == 0) reds[wave][nf*16 + r] = s;
  }
  __syncthreads();
  if (tid < 32) {
    int row = tid;
    float S = 0.f;
    #pragma unroll
    for (int w2 = 0; w2 < 8; w2++) S += reds[w2][row];
    float mfin = musd[row][7];
    float inv = 1.0f / S;
    size_t fb = ((size_t)(b*NH + h)*SEQ + n0 + row)*8;
    #pragma unroll
    for (int c = 0; c < 8; c++)
      F[fb + c] = __expf(musd[row][c] - mfin) * inv;
  }
}

// ---------------------------------------------------------------------------
// K_attn: dequant-transpose P[b][h][n][m] u16 * F -> attn[b][n][m][h] f32.
// One thread per (b,n,m): 16 coalesced u16 loads + 16 L2-hot F loads,
// 4 contiguous float4 stores.
// ---------------------------------------------------------------------------
__global__ __launch_bounds__(256) void k_attn_write(
    const unsigned short* __restrict__ P, const float* __restrict__ F,
    float* __restrict__ attn)
{
  int T = blockIdx.x*256 + threadIdx.x;
  int b = T >> 20, rem = T & 1048575;
  int n = rem >> 10, m = rem & 1023;
  int c = m >> 7;
  const size_t pb = ((size_t)(b*NH)*SEQ + n)*SEQ + m;
  const size_t fb = ((size_t)(b*NH)*SEQ + n)*8 + c;
  float v[16];
  #pragma unroll
  for (int h = 0; h < 16; h++)
    v[h] = (float)P[pb + (size_t)h*SEQ*SEQ] * F[fb + (size_t)h*SEQ*8];
  size_t ob = ((size_t)(b*SEQ + n)*SEQ + m)*16;
  #pragma unroll
  for (int g = 0; g < 4; g++)
    *(float4*)(attn + ob + g*4) = make_float4(v[g*4], v[g*4+1], v[g*4+2], v[g*4+3]);
}

// ---------------------------------------------------------------------------
// K4: PV gemm per (b,h):  OA[n][d] = sum_c F[n][c] * sum_{m in c} P_u16 * V
// 64n x 64d per block (512 blocks); exact byte-split planes of stored u16;
// per-chunk fold accF += acc * F.  Vt staged via gl_lds16.  XCD-chunked
// block swizzle: each XCD serves 4 contiguous (b,h) Vt panels (L2-resident).
// ---------------------------------------------------------------------------
__global__ __launch_bounds__(256) void k_pv(
    const unsigned short* __restrict__ P, const float* __restrict__ F,
    const unsigned short* __restrict__ Vthi, const unsigned short* __restrict__ Vtlo,
    unsigned short* __restrict__ OAhi, unsigned short* __restrict__ OAlo)
{
  int id = blockIdx.x + 16*(blockIdx.y + 16*blockIdx.z);   // 512 blocks
  id = (id & 7)*64 + (id >> 3);                            // XCD chunked
  int nt = id & 15, h = (id >> 4) & 15, b = id >> 8;
  int n0 = nt * 64;
  __shared__ unsigned short sPa[64*32], sPb[64*32], sVh[64*32], sVl[64*32];
  const int tid = threadIdx.x, lane = tid & 63, wave = tid >> 6;
  const int wm = wave & 1, wn = wave >> 1;
  const int r = lane & 15, q = lane >> 4;
  const int crow = lane >> 2;
  const int cgsw = ((lane & 3) ^ ((crow >> 1) & 3)) * 8;   // swizzled src group
  const int qsw = (q ^ ((r >> 1) & 3)) * 8;                // swizzled read group
  const size_t pbase = ((size_t)(b*NH + h))*SEQ*SEQ;
  const size_t vbase = ((size_t)(b*NH + h))*HD*SEQ;
  const size_t fbase = ((size_t)(b*NH + h))*SEQ*8;

  f32x4 acc[2][2], accF[2][2];
  #pragma unroll
  for (int i = 0; i < 2; i++)
    #pragma unroll
    for (int j = 0; j < 2; j++) {
      acc[i][j][0]=0.f; acc[i][j][1]=0.f; acc[i][j][2]=0.f; acc[i][j][3]=0.f;
      accF[i][j][0]=0.f; accF[i][j][1]=0.f; accF[i][j][2]=0.f; accF[i][j][3]=0.f;
    }

  for (int k0 = 0; k0 < SEQ; k0 += 32) {
    #pragma unroll
    for (int t = 0; t < 2; t++) {
      int c = wave + t*4;
      const unsigned short* gb = (c < 4) ? Vthi : Vtlo;
      unsigned short* sb = (c < 4) ? (unsigned short*)sVh : (unsigned short*)sVl;
      int rr = c & 3;
      int row = rr*16 + crow;
      gl_lds16(gb + vbase + (size_t)row*SEQ + k0 + cgsw, sb + rr*512);
    }
    {
      int row = tid >> 2, g = tid & 3, ch = g * 8;
      int gp = (g ^ ((row >> 1) & 3)) * 8;                 // swizzled LDS slot
      uint4 v = *(const uint4*)(P + pbase + (size_t)(n0 + row)*SEQ + k0 + ch);
      unsigned int wds[4] = {v.x, v.y, v.z, v.w};
      unsigned int pa[4], pb4[4];
      #pragma unroll
      for (int e = 0; e < 4; e++) {
        unsigned int lo16 = wds[e] & 0xFFFFu;
        unsigned int hi16 = wds[e] >> 16;
        unsigned int a0 = __builtin_bit_cast(uint32_t, (float)(lo16 & 0xFF00u)) >> 16;
        unsigned int b0 = __builtin_bit_cast(uint32_t, (float)(lo16 & 0x00FFu)) >> 16;
        unsigned int a1 = __builtin_bit_cast(uint32_t, (float)(hi16 & 0xFF00u)) >> 16;
        unsigned int b1 = __builtin_bit_cast(uint32_t, (float)(hi16 & 0x00FFu)) >> 16;
        pa[e]  = a0 | (a1 << 16);
        pb4[e] = b0 | (b1 << 16);
      }
      *(uint4*)(sPa + row*32 + gp) = make_uint4(pa[0],pa[1],pa[2],pa[3]);
      *(uint4*)(sPb + row*32 + gp) = make_uint4(pb4[0],pb4[1],pb4[2],pb4[3]);
    }
    __syncthreads();
    bf16x8 pa[2], pb2[2], vh[2], vl[2];
    #pragma unroll
    for (int i = 0; i < 2; i++) {
      int off = (wm*32 + i*16 + r)*32 + qsw;
      pa[i]  = *(const bf16x8*)(sPa + off);
      pb2[i] = *(const bf16x8*)(sPb + off);
    }
    #pragma unroll
    for (int j = 0; j < 2; j++) {
      int off = (wn*32 + j*16 + r)*32 + qsw;
      vh[j] = *(const bf16x8*)(sVh + off);
      vl[j] = *(const bf16x8*)(sVl + off);
    }
    #pragma unroll
    for (int i = 0; i < 2; i++)
      #pragma unroll
      for (int j = 0; j < 2; j++) {
        acc[i][j] = MFMA16(pa[i],  vh[j], acc[i][j]);
        acc[i][j] = MFMA16(pb2[i], vh[j], acc[i][j]);
        acc[i][j] = MFMA16(pa[i],  vl[j], acc[i][j]);
      }
    if ((k0 & 127) == 96) {                // end of 128-m chunk: fold with F
      int c = k0 >> 7;
      #pragma unroll
      for (int i = 0; i < 2; i++)
        #pragma unroll
        for (int t = 0; t < 4; t++) {
          int nn = n0 + wm*32 + i*16 + q*4 + t;
          float Fv = F[fbase + (size_t)nn*8 + c];
          #pragma unroll
          for (int j = 0; j < 2; j++) {
            accF[i][j][t] += acc[i][j][t] * Fv;
            acc[i][j][t] = 0.f;
          }
        }
    }
    __syncthreads();
  }
  #pragma unroll
  for (int i = 0; i < 2; i++)
    #pragma unroll
    for (int t = 0; t < 4; t++) {
      int nn = n0 + wm*32 + i*16 + q*4 + t;
      #pragma unroll
      for (int j = 0; j < 2; j++) {
        int d = wn*32 + j*16 + r;
        float val = accF[i][j][t];
        size_t o = (size_t)(b*SEQ + nn)*CDIM + h*HD + d;
        unsigned short hb = f2bf(val);
        OAhi[o] = hb; OAlo[o] = f2bf(val - bf2f(hb));
      }
    }
}

// ---------------------------------------------------------------------------
extern "C" void kernel_launch(void* const* d_in, const int* in_sizes, int n_in,
                              void* d_out, int out_size, void* d_ws, size_t ws_size,
                              hipStream_t stream)
{
  const float* x   = (const float*)d_in[0];
  const float* Wq  = (const float*)d_in[1];
  const float* bq  = (const float*)d_in[2];
  const float* Wkv = (const float*)d_in[3];
  const float* bkv = (const float*)d_in[4];
  const float* Wp  = (const float*)d_in[5];
  const float* bp  = (const float*)d_in[6];

  float* out  = (float*)d_out;
  float* attn = out + (size_t)ROWS*CDIM;

  char* w = (char*)d_ws;
  unsigned short* Xhi  = (unsigned short*)w; w += (size_t)ROWS*CDIM*2;
  unsigned short* Xlo  = (unsigned short*)w; w += (size_t)ROWS*CDIM*2;
  unsigned short* Whi  = (unsigned short*)w; w += (size_t)4096*CDIM*2;
  unsigned short* Wlo  = (unsigned short*)w; w += (size_t)4096*CDIM*2;
  unsigned short* Qhi  = (unsigned short*)w; w += (size_t)ROWS*CDIM*2;
  unsigned short* Qlo  = (unsigned short*)w; w += (size_t)ROWS*CDIM*2;
  unsigned short* Khi  = (unsigned short*)w; w += (size_t)ROWS*CDIM*2;
  unsigned short* Klo  = (unsigned short*)w; w += (size_t)ROWS*CDIM*2;
  unsigned short* Vthi = (unsigned short*)w; w += (size_t)NB*NH*HD*SEQ*2;
  unsigned short* Vtlo = (unsigned short*)w; w += (size_t)NB*NH*HD*SEQ*2;
  unsigned short* OAhi = (unsigned short*)w; w += (size_t)ROWS*CDIM*2;
  unsigned short* OAlo = (unsigned short*)w; w += (size_t)ROWS*CDIM*2;
  unsigned short* P    = (unsigned short*)w; w += (size_t)NB*NH*SEQ*SEQ*2;
  float*          Ftab = (float*)w;          w += (size_t)NB*NH*SEQ*8*4;

  k_convert<<<dim3((ROWS*CDIM/4 + 4096*CDIM/4)/256), 256, 0, stream>>>(
      x, Wq, Wkv, Wp, Xhi, Xlo, Whi, Wlo);

  k_gemm_qkv<<<dim3(3072/64, 2048/128), 256, 0, stream>>>(
      Xhi, Xlo, Whi, Wlo, bq, bkv, Qhi, Qlo, Khi, Klo, Vthi, Vtlo);

  k_logits_softmax<<<dim3(SEQ/32, NH, NB), 512, 0, stream>>>(
      Qhi, Qlo, Khi, Klo, P, Ftab);

  k_pv<<<dim3(SEQ/64, NH, NB), 256, 0, stream>>>(P, Ftab, Vthi, Vtlo, OAhi, OAlo);

  k_gemm_out<<<dim3(1024/64, 2048/128), 512, 0, stream>>>(
      OAhi, OAlo, Whi + (size_t)3072*CDIM, Wlo + (size_t)3072*CDIM, bp, out);

  k_attn_write<<<dim3((NB*SEQ*SEQ)/256), 256, 0, stream>>>(P, Ftab, attn);
}

// Round 9
// 345.556 us; speedup vs baseline: 1.0894x; 1.0134x over previous
//
#include <hip/hip_runtime.h>
#include <hip/hip_bf16.h>
#include <stdint.h>

// ---------------------------------------------------------------------------
// MultiHeadAttention on MI355X (gfx950).
// b=2, n=1024, DIM=1024, H=16, dh=64.  Outputs: out (2M f32) ++ attn (33.5M f32).
// GEMMs: bf16 MFMA 16x16x32, hi/lo split (3 MFMAs) => ~fp32 accuracy.
// R10: qkv standalone, LDS-bounce epilogue, V transposed once (Vt).
// R11: k_convert vectorized; XCD-chunked swizzle on attention kernels. 350us.
// R12: PV FUSED into the softmax kernel; k_pv deleted.  64-m chunks; K and
//      Vt double-buffered in LDS; per chunk: QK^T -> row-max -> quantize
//      (u16 P -> global + bank-swizzled sP LDS) -> PV MFMAs with online
//      accO rescale (exp(m_old-m_new) via fac[] LDS; identical math to the
//      F-fold, so numerics unchanged).  2 barriers/chunk.  LDS ~77KB =>
//      2 blocks/CU.  F table now 16 chunks/row (attn_write m>>6).
// ---------------------------------------------------------------------------

#define NB   2
#define SEQ  1024
#define CDIM 1024
#define NH   16
#define HD   64
#define ROWS (NB*SEQ)          // 2048
#define ATT_SCALE 0.125f       // 64^-0.5

typedef __attribute__((ext_vector_type(8))) short bf16x8;
typedef __attribute__((ext_vector_type(4))) float f32x4;

#define MFMA16(a,b,c) __builtin_amdgcn_mfma_f32_16x16x32_bf16((a),(b),(c),0,0,0)

static __device__ __forceinline__ unsigned short f2bf(float f) {
  uint32_t x = __builtin_bit_cast(uint32_t, f);
  return (unsigned short)((x + 0x7fffu + ((x >> 16) & 1u)) >> 16);   // RTN-even
}
static __device__ __forceinline__ float bf2f(unsigned short u) {
  uint32_t x = ((uint32_t)u) << 16;
  return __builtin_bit_cast(float, x);
}

// async global->LDS DMA, 16B/lane; lds dest = wave-uniform base + lane*16
static __device__ __forceinline__ void gl_lds16(const unsigned short* g,
                                                unsigned short* l) {
  __builtin_amdgcn_global_load_lds(
      (const __attribute__((address_space(1))) unsigned int*)g,
      (__attribute__((address_space(3))) unsigned int*)l,
      16, 0, 0);
}

// ---------------------------------------------------------------------------
// K0: fp32 -> bf16 hi/lo split for x and concatenated W = [Wq; Wkv; Wp]
// Vectorized: 4 f32 per thread, packed uint2 stores per plane.
// ---------------------------------------------------------------------------
__global__ __launch_bounds__(256) void k_convert(
    const float* __restrict__ x, const float* __restrict__ Wq,
    const float* __restrict__ Wkv, const float* __restrict__ Wp,
    unsigned short* __restrict__ Xhi, unsigned short* __restrict__ Xlo,
    unsigned short* __restrict__ Whi, unsigned short* __restrict__ Wlo)
{
  const int NX4 = ROWS*CDIM/4;       // 524288
  const int NW4 = 4096*CDIM/4;       // 1048576
  int i = blockIdx.x*256 + threadIdx.x;
  float4 f;
  unsigned short* dh;
  unsigned short* dl;
  size_t o4;
  if (i < NX4) {
    f = ((const float4*)x)[i];
    dh = Xhi; dl = Xlo; o4 = (size_t)i*4;
  } else if (i < NX4 + NW4) {
    int w4 = i - NX4;
    int j = w4 >> 8;                 // row (w4*4 / 1024)
    int c4 = w4 & 255;               // col/4
    const float* ws = (j < 1024) ? Wq + (size_t)j*1024
                    : (j < 3072) ? Wkv + (size_t)(j-1024)*1024
                                 : Wp + (size_t)(j-3072)*1024;
    f = ((const float4*)ws)[c4];
    dh = Whi; dl = Wlo; o4 = (size_t)w4*4;
  } else return;
  float fv[4] = {f.x, f.y, f.z, f.w};
  unsigned int hp[2], lp[2];
  #pragma unroll
  for (int e = 0; e < 2; e++) {
    unsigned short h0 = f2bf(fv[e*2]),   l0 = f2bf(fv[e*2]   - bf2f(h0));
    unsigned short h1 = f2bf(fv[e*2+1]), l1 = f2bf(fv[e*2+1] - bf2f(h1));
    hp[e] = (unsigned)h0 | ((unsigned)h1 << 16);
    lp[e] = (unsigned)l0 | ((unsigned)l1 << 16);
  }
  *(uint2*)(dh + o4) = make_uint2(hp[0], hp[1]);
  *(uint2*)(dl + o4) = make_uint2(lp[0], lp[1]);
}

// ---------------------------------------------------------------------------
// K1: QKV GEMM, standalone.  128x64 tile, 2x2 waves (FM=4, FN=2), BK=32,
// swizzled LDS.  Epilogue: LDS bounce -> coalesced uint4 stores.
//   seg 0/1 (Q/K): bounce [128 m][72 pad] -> Q/K[m][n] rows.
//   seg 2 (V):     bounce [64 d][136 pad] (transposed) -> Vt[d][m] rows.
// ---------------------------------------------------------------------------
__global__ __launch_bounds__(256) void k_gemm_qkv(
    const unsigned short* __restrict__ Xhi, const unsigned short* __restrict__ Xlo,
    const unsigned short* __restrict__ Whi, const unsigned short* __restrict__ Wlo,
    const float* __restrict__ bq, const float* __restrict__ bkv,
    unsigned short* __restrict__ Qhi, unsigned short* __restrict__ Qlo,
    unsigned short* __restrict__ Khi, unsigned short* __restrict__ Klo,
    unsigned short* __restrict__ Vthi, unsigned short* __restrict__ Vtlo)
{
  __shared__ unsigned short smem[12288];      // staging 24KB; bounce reuses it
  unsigned short* sAh = smem;                 // 128*32
  unsigned short* sAl = smem + 4096;
  unsigned short* sBh = smem + 8192;          // 64*32
  unsigned short* sBl = smem + 10240;
  const int tid = threadIdx.x, lane = tid & 63, wave = tid >> 6;
  const int wm = wave & 1, wn = wave >> 1;
  const int bn = blockIdx.x * 64, bm = blockIdx.y * 128;
  const int r = lane & 15, q = lane >> 4;
  const int crow = lane >> 2;
  const int cgsw = ((lane & 3) ^ ((crow >> 1) & 3)) * 8;
  const int qsw = (q ^ ((r >> 1) & 3)) * 8;

  f32x4 acc[4][2];
  #pragma unroll
  for (int i = 0; i < 4; i++)
    #pragma unroll
    for (int j = 0; j < 2; j++) {
      acc[i][j][0]=0.f; acc[i][j][1]=0.f; acc[i][j][2]=0.f; acc[i][j][3]=0.f;
    }

  for (int k0 = 0; k0 < CDIM; k0 += 32) {
    #pragma unroll
    for (int t = 0; t < 6; t++) {            // TOT=24 chunks / 4 waves
      int c = wave + t*4;
      const unsigned short* gb; unsigned short* sb; int rr, grow;
      if (c < 8)        { gb=Xhi; sb=sAh; rr=c;    grow=bm; }
      else if (c < 16)  { gb=Xlo; sb=sAl; rr=c-8;  grow=bm; }
      else if (c < 20)  { gb=Whi; sb=sBh; rr=c-16; grow=bn; }
      else              { gb=Wlo; sb=sBl; rr=c-20; grow=bn; }
      int row = rr*16 + crow;
      gl_lds16(gb + (size_t)(grow + row)*CDIM + k0 + cgsw, sb + rr*512);
    }
    __syncthreads();
    bf16x8 ah[4], al[4], bh[2], bl[2];
    #pragma unroll
    for (int i = 0; i < 4; i++) {
      int oa = (wm*64 + i*16 + r)*32 + qsw;
      ah[i] = *(const bf16x8*)(sAh + oa);
      al[i] = *(const bf16x8*)(sAl + oa);
    }
    #pragma unroll
    for (int j = 0; j < 2; j++) {
      int ob = (wn*32 + j*16 + r)*32 + qsw;
      bh[j] = *(const bf16x8*)(sBh + ob);
      bl[j] = *(const bf16x8*)(sBl + ob);
    }
    #pragma unroll
    for (int i = 0; i < 4; i++)
      #pragma unroll
      for (int j = 0; j < 2; j++) {
        acc[i][j] = MFMA16(ah[i], bh[j], acc[i][j]);
        acc[i][j] = MFMA16(ah[i], bl[j], acc[i][j]);
        acc[i][j] = MFMA16(al[i], bh[j], acc[i][j]);
      }
    __syncthreads();
  }

  // ---- epilogue: bias+scale, hi/lo split, LDS bounce, coalesced stores
  const int seg = bn >> 10;                       // 0=Q 1=K 2=V
  const float* bias = (seg == 0) ? (bq + bn) : (bkv + (bn - 1024));
  const float scl = (seg == 0) ? ATT_SCALE : 1.0f;
  float bj[2] = { bias[wn*32 + r], bias[wn*32 + 16 + r] };

  if (seg < 2) {
    unsigned short* dh = (seg == 0) ? Qhi : Khi;
    unsigned short* dl = (seg == 0) ? Qlo : Klo;
    const int ncol = bn & 1023;
    #pragma unroll
    for (int p = 0; p < 2; p++) {
      #pragma unroll
      for (int i = 0; i < 4; i++)
        #pragma unroll
        for (int j = 0; j < 2; j++)
          #pragma unroll
          for (int t = 0; t < 4; t++) {
            int m_l = wm*64 + i*16 + q*4 + t;
            int n_l = wn*32 + j*16 + r;
            float v2 = (acc[i][j][t] + bj[j]) * scl;
            unsigned short hv = f2bf(v2);
            unsigned short val = (p == 0) ? hv : f2bf(v2 - bf2f(hv));
            smem[m_l*72 + n_l] = val;
          }
      __syncthreads();
      unsigned short* dst = (p == 0) ? dh : dl;
      #pragma unroll
      for (int u = 0; u < 4; u++) {
        int s = u*256 + tid;
        int m_l = s >> 3, nseg = s & 7;
        uint4 vv = *(const uint4*)(smem + m_l*72 + nseg*8);
        *(uint4*)(dst + (size_t)(bm + m_l)*1024 + ncol + nseg*8) = vv;
      }
      __syncthreads();
    }
  } else {
    // V: transposed bounce [64 d][136 pad] -> Vt[((b*NH+h)*HD+d)*SEQ + m]
    const int h = (bn - 2048) >> 6;
    const int b = bm >> 10, mm = bm & 1023;
    const size_t vtb = ((size_t)((b*NH + h)*HD))*SEQ + mm;
    #pragma unroll
    for (int p = 0; p < 2; p++) {
      #pragma unroll
      for (int i = 0; i < 4; i++)
        #pragma unroll
        for (int j = 0; j < 2; j++)
          #pragma unroll
          for (int t = 0; t < 4; t++) {
            int m_l = wm*64 + i*16 + q*4 + t;
            int d_l = wn*32 + j*16 + r;
            float v2 = acc[i][j][t] + bj[j];
            unsigned short hv = f2bf(v2);
            unsigned short val = (p == 0) ? hv : f2bf(v2 - bf2f(hv));
            smem[d_l*136 + m_l] = val;
          }
      __syncthreads();
      unsigned short* dst = (p == 0) ? Vthi : Vtlo;
      #pragma unroll
      for (int u = 0; u < 4; u++) {
        int s = u*256 + tid;
        int d_l = s >> 4, mseg = s & 15;
        uint4 vv = *(const uint4*)(smem + d_l*136 + mseg*8);
        *(uint4*)(dst + vtb + (size_t)d_l*SEQ + mseg*8) = vv;
      }
      __syncthreads();
    }
  }
}

// ---------------------------------------------------------------------------
// Templated NT-GEMM core (split bf16, BK=32, wave grid WM x WN) -- k_gemm_out.
// ---------------------------------------------------------------------------
struct EpiOut {
  const float* bp; float* out;
  __device__ __forceinline__ void operator()(int m, int n, float v) const {
    out[(size_t)m*1024 + n] = v + bp[n];
  }
};

template <int BM, int BN, int WM, int WN, class Epi>
__device__ __forceinline__ void gemm_core(
    const unsigned short* __restrict__ Ahi, const unsigned short* __restrict__ Alo, int lda,
    const unsigned short* __restrict__ Bhi, const unsigned short* __restrict__ Blo, int ldb,
    int K, const Epi& epi)
{
  constexpr int WAVES = WM*WN;
  constexpr int FM = BM/(WM*16), FN = BN/(WN*16);
  constexpr int CA = BM/16, CB = BN/16;
  constexpr int TOT = 2*(CA+CB);
  __shared__ unsigned short sAh[BM*32], sAl[BM*32], sBh[BN*32], sBl[BN*32];
  const int tid  = threadIdx.x;
  const int lane = tid & 63, wave = tid >> 6;
  const int wm = wave % WM, wn = wave / WM;
  const int bn = blockIdx.x * BN, bm = blockIdx.y * BM;
  const int r = lane & 15, q = lane >> 4;
  const int crow = lane >> 2;
  const int cgsw = ((lane & 3) ^ ((crow >> 1) & 3)) * 8;   // swizzled src group
  const int qsw = (q ^ ((r >> 1) & 3)) * 8;                // swizzled read group

  f32x4 acc[FM][FN];
  #pragma unroll
  for (int i = 0; i < FM; i++)
    #pragma unroll
    for (int j = 0; j < FN; j++) {
      acc[i][j][0]=0.f; acc[i][j][1]=0.f; acc[i][j][2]=0.f; acc[i][j][3]=0.f;
    }

  for (int k0 = 0; k0 < K; k0 += 32) {
    #pragma unroll
    for (int t = 0; t < TOT/WAVES; t++) {
      int c = wave + t*WAVES;
      const unsigned short* gb; unsigned short* sb; int rr, grow, ld;
      if (c < CA)            { gb=Ahi; sb=sAh; rr=c;         grow=bm; ld=lda; }
      else if (c < 2*CA)     { gb=Alo; sb=sAl; rr=c-CA;      grow=bm; ld=lda; }
      else if (c < 2*CA+CB)  { gb=Bhi; sb=sBh; rr=c-2*CA;    grow=bn; ld=ldb; }
      else                   { gb=Blo; sb=sBl; rr=c-2*CA-CB; grow=bn; ld=ldb; }
      int row = rr*16 + crow;
      gl_lds16(gb + (size_t)(grow + row)*ld + k0 + cgsw, sb + rr*512);
    }
    __syncthreads();
    bf16x8 ah[FM], al[FM], bh[FN], bl[FN];
    #pragma unroll
    for (int i = 0; i < FM; i++) {
      int oa = (wm*(BM/WM) + i*16 + r)*32 + qsw;
      ah[i] = *(const bf16x8*)(sAh + oa);
      al[i] = *(const bf16x8*)(sAl + oa);
    }
    #pragma unroll
    for (int j = 0; j < FN; j++) {
      int ob = (wn*(BN/WN) + j*16 + r)*32 + qsw;
      bh[j] = *(const bf16x8*)(sBh + ob);
      bl[j] = *(const bf16x8*)(sBl + ob);
    }
    #pragma unroll
    for (int i = 0; i < FM; i++)
      #pragma unroll
      for (int j = 0; j < FN; j++) {
        acc[i][j] = MFMA16(ah[i], bh[j], acc[i][j]);
        acc[i][j] = MFMA16(ah[i], bl[j], acc[i][j]);
        acc[i][j] = MFMA16(al[i], bh[j], acc[i][j]);
      }
    __syncthreads();
  }
  #pragma unroll
  for (int i = 0; i < FM; i++)
    #pragma unroll
    for (int j = 0; j < FN; j++)
      #pragma unroll
      for (int t = 0; t < 4; t++)
        epi(bm + wm*(BM/WM) + i*16 + q*4 + t, bn + wn*(BN/WN) + j*16 + r, acc[i][j][t]);
}

__global__ __launch_bounds__(512) void k_gemm_out(
    const unsigned short* OAhi, const unsigned short* OAlo,
    const unsigned short* Wphi, const unsigned short* Wplo,
    const float* bp, float* out)
{
  EpiOut e{bp, out};
  gemm_core<128,64,4,2>(OAhi, OAlo, CDIM, Wphi, Wplo, CDIM, CDIM, e);
}

// ---------------------------------------------------------------------------
// K23: FUSED softmax+PV.  Block = 32 n-rows x one (b,h); 512 thr (8 waves).
// 16 chunks of 64 m.  K and Vt double-buffered (dseg-swizzled, gl_lds16).
// Wave roles: QK^T n-half = wave>>2, m-tile = wave&3; PV same n-half,
// d-tile = wave&3.  Per chunk: QK^T -> row max (redm dbuf) -> quantize u16
// (global P + bank-swizzled sP) -> PV with online accO rescale via fac[].
// End: S reduce -> invS, F table (16 chunks); accO*invS -> OA hi/lo.
// musd/fac/invS/reds overlay dead sQ space (Q is in regs after chunk 0).
// ---------------------------------------------------------------------------
__global__ __launch_bounds__(512, 4) void k_attn_fused(
    const unsigned short* __restrict__ Qhi, const unsigned short* __restrict__ Qlo,
    const unsigned short* __restrict__ Khi, const unsigned short* __restrict__ Klo,
    const unsigned short* __restrict__ Vthi, const unsigned short* __restrict__ Vtlo,
    unsigned short* __restrict__ P, float* __restrict__ F,
    unsigned short* __restrict__ OAhi, unsigned short* __restrict__ OAlo)
{
  int id = blockIdx.x + 32*(blockIdx.y + 16*blockIdx.z);   // 1024 blocks
  id = (id & 7)*128 + (id >> 3);                           // XCD chunked
  const int nt = id & 31, h = (id >> 5) & 15, b = id >> 9;
  const int n0 = nt*32, col0 = h*HD;
  __shared__ unsigned short sQ[2*2048];        // 8KB; scalars overlaid later
  __shared__ unsigned short sK[2][2*4096];     // 32KB [buf][plane][64m x 64k]
  __shared__ unsigned short sV[2][2*4096];     // 32KB [buf][plane][64d x 64m]
  __shared__ unsigned short sP[32*64];         // 4KB u16, bank-swizzled
  __shared__ float redm[2][8][16];             // 1KB per-chunk wave max
  float* musd  = (float*)sQ;                   // [32][16]  (2048B)
  float* fac   = (float*)(sQ + 1024);          // [32]      (byte 2048)
  float* invSs = (float*)(sQ + 1088);          // [32]      (byte 2176)
  float* redsS = (float*)(sQ + 1152);          // [8][16]   (byte 2304..2816)
  const int tid = threadIdx.x, lane = tid & 63, wave = tid >> 6;
  const int r = lane & 15, q = lane >> 4;
  const int drow = lane >> 3, dseg = (lane & 7) ^ drow;   // DMA swizzle
  const int sw = r & 7;                                   // read swizzle
  const int nf = wave >> 2;      // n-half (QK^T and PV)
  const int mt = wave & 3;       // m-tile (QK^T) / d-tile (PV)
  const size_t qrow0 = (size_t)b*SEQ + n0;
  const size_t krow0 = (size_t)b*SEQ;
  const size_t vt0   = (size_t)(b*NH + h)*HD;

  auto stageK = [&](int c, int buf) {
    #pragma unroll
    for (int u = 0; u < 2; u++) {
      int cc = wave*2 + u;               // 0..15
      int p = cc >> 3, t = cc & 7;
      const unsigned short* g = p ? Klo : Khi;
      gl_lds16(g + (krow0 + (size_t)c*64 + t*8 + drow)*CDIM + col0 + dseg*8,
               sK[buf] + p*4096 + t*512);
    }
  };
  auto stageV = [&](int c, int buf) {
    #pragma unroll
    for (int u = 0; u < 2; u++) {
      int cc = wave*2 + u;
      int p = cc >> 3, t = cc & 7;
      const unsigned short* g = p ? Vtlo : Vthi;
      gl_lds16(g + (vt0 + t*8 + drow)*SEQ + (size_t)c*64 + dseg*8,
               sV[buf] + p*4096 + t*512);
    }
  };

  {   // initial: Q + chunk 0 of K and V
    int p = wave >> 2, t = wave & 3;
    const unsigned short* g = p ? Qlo : Qhi;
    gl_lds16(g + (qrow0 + t*8 + drow)*CDIM + col0 + dseg*8, sQ + p*2048 + t*512);
    stageK(0, 0); stageV(0, 0);
  }
  __syncthreads();

  // Q fragments (one n-half per wave) -> registers for the whole kernel
  bf16x8 qh[2], ql[2];
  #pragma unroll
  for (int ks = 0; ks < 2; ks++) {
    int phys = (nf*16 + r)*64 + (((ks*4 + q) ^ sw))*8;
    qh[ks] = *(const bf16x8*)(sQ + phys);
    ql[ks] = *(const bf16x8*)(sQ + 2048 + phys);
  }

  float m_run = -1e30f, s_run = 0.f;
  f32x4 accO; accO[0]=0.f; accO[1]=0.f; accO[2]=0.f; accO[3]=0.f;
  const size_t pbase = ((size_t)(b*NH + h)*SEQ + n0)*SEQ;

  for (int c = 0; c < 16; c++) {
    const int buf = c & 1;
    // a. QK^T for this wave's (nf, mt)
    bf16x8 kh[2], kl[2];
    #pragma unroll
    for (int ks = 0; ks < 2; ks++) {
      int phys = (mt*16 + r)*64 + (((ks*4 + q) ^ sw))*8;
      kh[ks] = *(const bf16x8*)(sK[buf] + phys);
      kl[ks] = *(const bf16x8*)(sK[buf] + 4096 + phys);
    }
    f32x4 acc; acc[0]=0.f; acc[1]=0.f; acc[2]=0.f; acc[3]=0.f;
    #pragma unroll
    for (int ks = 0; ks < 2; ks++) {
      acc = MFMA16(kh[ks], qh[ks], acc);
      acc = MFMA16(kl[ks], qh[ks], acc);
      acc = MFMA16(kh[ks], ql[ks], acc);
    }
    // b. wave-level row max partials
    {
      float v = fmaxf(fmaxf(acc[0], acc[1]), fmaxf(acc[2], acc[3]));
      v = fmaxf(v, __shfl_xor(v, 16));
      v = fmaxf(v, __shfl_xor(v, 32));
      if (q == 0) redm[buf][wave][r] = v;
    }
    __syncthreads();                     // BARRIER-1
    // d. prefetch next chunk (K and V)
    if (c < 15) { stageK(c+1, buf^1); stageV(c+1, buf^1); }
    // e. chunk max -> quantize -> global P + sP; fac/musd bookkeeping
    {
      const int wg = nf*4;
      float mc = redm[buf][wg][r];
      #pragma unroll
      for (int w2 = 1; w2 < 4; w2++) mc = fmaxf(mc, redm[buf][wg + w2][r]);
      float mnew = fmaxf(m_run, mc);
      if (wave == wg && q == 0) {        // one writer per row
        fac[nf*16 + r] = __expf(m_run - mnew);
        musd[(nf*16 + r)*16 + c] = mnew;
      }
      unsigned s0 = (unsigned)(__expf(acc[0]-mnew)*65535.f + 0.5f);
      unsigned s1 = (unsigned)(__expf(acc[1]-mnew)*65535.f + 0.5f);
      unsigned s2 = (unsigned)(__expf(acc[2]-mnew)*65535.f + 0.5f);
      unsigned s3 = (unsigned)(__expf(acc[3]-mnew)*65535.f + 0.5f);
      uint2 pk = make_uint2(s0 | (s1 << 16), s2 | (s3 << 16));
      const int row = nf*16 + r;
      *(uint2*)(P + pbase + (size_t)row*SEQ + c*64 + mt*16 + q*4) = pk;
      int gw = mt*2 + (q >> 1);                       // 16B group of m
      *(uint2*)(sP + row*64 + ((gw ^ (r & 7)) << 3) + (q & 1)*4) = pk;
      s_run = s_run*__expf(m_run - mnew) + (float)(s0 + s1 + s2 + s3);
      m_run = mnew;
    }
    __syncthreads();                     // BARRIER-2
    // g. PV: rescale accO, then 2 k-steps x 3 MFMA from sP (in-reg dequant) + sV
    {
      float f0 = fac[nf*16 + q*4 + 0];
      float f1 = fac[nf*16 + q*4 + 1];
      float f2 = fac[nf*16 + q*4 + 2];
      float f3 = fac[nf*16 + q*4 + 3];
      accO[0] *= f0; accO[1] *= f1; accO[2] *= f2; accO[3] *= f3;
      #pragma unroll
      for (int kk = 0; kk < 2; kk++) {
        int gr = kk*4 + q;
        uint4 pv4 = *(const uint4*)(sP + (nf*16 + r)*64 + ((gr ^ (r & 7)) << 3));
        unsigned int wds[4] = {pv4.x, pv4.y, pv4.z, pv4.w};
        unsigned int pa_[4], pb_[4];
        #pragma unroll
        for (int e = 0; e < 4; e++) {
          unsigned int lo16 = wds[e] & 0xFFFFu;
          unsigned int hi16 = wds[e] >> 16;
          unsigned int a0 = __builtin_bit_cast(uint32_t, (float)(lo16 & 0xFF00u)) >> 16;
          unsigned int b0 = __builtin_bit_cast(uint32_t, (float)(lo16 & 0x00FFu)) >> 16;
          unsigned int a1 = __builtin_bit_cast(uint32_t, (float)(hi16 & 0xFF00u)) >> 16;
          unsigned int b1 = __builtin_bit_cast(uint32_t, (float)(hi16 & 0x00FFu)) >> 16;
          pa_[e] = a0 | (a1 << 16);
          pb_[e] = b0 | (b1 << 16);
        }
        bf16x8 pa = __builtin_bit_cast(bf16x8, make_uint4(pa_[0],pa_[1],pa_[2],pa_[3]));
        bf16x8 pb = __builtin_bit_cast(bf16x8, make_uint4(pb_[0],pb_[1],pb_[2],pb_[3]));
        int physv = (mt*16 + r)*64 + (((kk*4 + q) ^ sw))*8;
        bf16x8 vh = *(const bf16x8*)(sV[buf] + physv);
        bf16x8 vl = *(const bf16x8*)(sV[buf] + 4096 + physv);
        accO = MFMA16(pa, vh, accO);
        accO = MFMA16(pb, vh, accO);
        accO = MFMA16(pa, vl, accO);
      }
    }
  }

  // ---- final sum reduction, invS + F table
  {
    float s = s_run;
    s += __shfl_xor(s, 16);
    s += __shfl_xor(s, 32);
    if (q == 0) redsS[wave*16 + r] = s;
  }
  __syncthreads();
  if (tid < 32) {
    int row = tid;
    int wg = (row >> 4)*4, rr = row & 15;
    float S = redsS[wg*16 + rr] + redsS[(wg+1)*16 + rr]
            + redsS[(wg+2)*16 + rr] + redsS[(wg+3)*16 + rr];
    float mfin = musd[row*16 + 15];
    float inv = 1.0f / S;
    invSs[row] = inv;
    size_t fb = ((size_t)(b*NH + h)*SEQ + n0 + row)*16;
    #pragma unroll
    for (int c = 0; c < 16; c++)
      F[fb + c] = __expf(musd[row*16 + c] - mfin) * inv;
  }
  __syncthreads();
  // ---- scale + OA store
  {
    float i0 = invSs[nf*16 + q*4 + 0];
    float i1 = invSs[nf*16 + q*4 + 1];
    float i2 = invSs[nf*16 + q*4 + 2];
    float i3 = invSs[nf*16 + q*4 + 3];
    float vals[4] = {accO[0]*i0, accO[1]*i1, accO[2]*i2, accO[3]*i3};
    #pragma unroll
    for (int t = 0; t < 4; t++) {
      int nn = n0 + nf*16 + q*4 + t;
      int d = mt*16 + r;
      size_t o = (size_t)(b*SEQ + nn)*CDIM + h*HD + d;
      unsigned short hb = f2bf(vals[t]);
      OAhi[o] = hb; OAlo[o] = f2bf(vals[t] - bf2f(hb));
    }
  }
}

// ---------------------------------------------------------------------------
// K_attn: dequant-transpose P[b][h][n][m] u16 * F -> attn[b][n][m][h] f32.
// One thread per (b,n,m): 16 coalesced u16 loads + 16 L2-hot F loads,
// 4 contiguous float4 stores.  F now has 16 chunks/row (m>>6).
// ---------------------------------------------------------------------------
__global__ __launch_bounds__(256) void k_attn_write(
    const unsigned short* __restrict__ P, const float* __restrict__ F,
    float* __restrict__ attn)
{
  int T = blockIdx.x*256 + threadIdx.x;
  int b = T >> 20, rem = T & 1048575;
  int n = rem >> 10, m = rem & 1023;
  int c = m >> 6;
  const size_t pb = ((size_t)(b*NH)*SEQ + n)*SEQ + m;
  const size_t fb = ((size_t)(b*NH)*SEQ + n)*16 + c;
  float v[16];
  #pragma unroll
  for (int h = 0; h < 16; h++)
    v[h] = (float)P[pb + (size_t)h*SEQ*SEQ] * F[fb + (size_t)h*SEQ*16];
  size_t ob = ((size_t)(b*SEQ + n)*SEQ + m)*16;
  #pragma unroll
  for (int g = 0; g < 4; g++)
    *(float4*)(attn + ob + g*4) = make_float4(v[g*4], v[g*4+1], v[g*4+2], v[g*4+3]);
}

// ---------------------------------------------------------------------------
extern "C" void kernel_launch(void* const* d_in, const int* in_sizes, int n_in,
                              void* d_out, int out_size, void* d_ws, size_t ws_size,
                              hipStream_t stream)
{
  const float* x   = (const float*)d_in[0];
  const float* Wq  = (const float*)d_in[1];
  const float* bq  = (const float*)d_in[2];
  const float* Wkv = (const float*)d_in[3];
  const float* bkv = (const float*)d_in[4];
  const float* Wp  = (const float*)d_in[5];
  const float* bp  = (const float*)d_in[6];

  float* out  = (float*)d_out;
  float* attn = out + (size_t)ROWS*CDIM;

  char* w = (char*)d_ws;
  unsigned short* Xhi  = (unsigned short*)w; w += (size_t)ROWS*CDIM*2;
  unsigned short* Xlo  = (unsigned short*)w; w += (size_t)ROWS*CDIM*2;
  unsigned short* Whi  = (unsigned short*)w; w += (size_t)4096*CDIM*2;
  unsigned short* Wlo  = (unsigned short*)w; w += (size_t)4096*CDIM*2;
  unsigned short* Qhi  = (unsigned short*)w; w += (size_t)ROWS*CDIM*2;
  unsigned short* Qlo  = (unsigned short*)w; w += (size_t)ROWS*CDIM*2;
  unsigned short* Khi  = (unsigned short*)w; w += (size_t)ROWS*CDIM*2;
  unsigned short* Klo  = (unsigned short*)w; w += (size_t)ROWS*CDIM*2;
  unsigned short* Vthi = (unsigned short*)w; w += (size_t)NB*NH*HD*SEQ*2;
  unsigned short* Vtlo = (unsigned short*)w; w += (size_t)NB*NH*HD*SEQ*2;
  unsigned short* OAhi = (unsigned short*)w; w += (size_t)ROWS*CDIM*2;
  unsigned short* OAlo = (unsigned short*)w; w += (size_t)ROWS*CDIM*2;
  unsigned short* P    = (unsigned short*)w; w += (size_t)NB*NH*SEQ*SEQ*2;
  float*          Ftab = (float*)w;          w += (size_t)NB*NH*SEQ*16*4;

  k_convert<<<dim3((ROWS*CDIM/4 + 4096*CDIM/4)/256), 256, 0, stream>>>(
      x, Wq, Wkv, Wp, Xhi, Xlo, Whi, Wlo);

  k_gemm_qkv<<<dim3(3072/64, 2048/128), 256, 0, stream>>>(
      Xhi, Xlo, Whi, Wlo, bq, bkv, Qhi, Qlo, Khi, Klo, Vthi, Vtlo);

  k_attn_fused<<<dim3(SEQ/32, NH, NB), 512, 0, stream>>>(
      Qhi, Qlo, Khi, Klo, Vthi, Vtlo, P, Ftab, OAhi, OAlo);

  k_gemm_out<<<dim3(1024/64, 2048/128), 512, 0, stream>>>(
      OAhi, OAlo, Whi + (size_t)3072*CDIM, Wlo + (size_t)3072*CDIM, bp, out);

  k_attn_write<<<dim3((NB*SEQ*SEQ)/256), 256, 0, stream>>>(P, Ftab, attn);
}

// Round 10
// 345.001 us; speedup vs baseline: 1.0912x; 1.0016x over previous
//
#include <hip/hip_runtime.h>
#include <hip/hip_bf16.h>
#include <stdint.h>

// ---------------------------------------------------------------------------
// MultiHeadAttention on MI355X (gfx950).
// b=2, n=1024, DIM=1024, H=16, dh=64.  Outputs: out (2M f32) ++ attn (33.5M f32).
// GEMMs: bf16 MFMA 16x16x32, hi/lo split (3 MFMAs) => ~fp32 accuracy.
// R11: k_convert vectorized; XCD-chunked swizzle on attention kernels.
// R12: PV fused into softmax kernel (345.6us).
// R13: k_gemm_qkv retiled 128x64 -> 128x128 KEEPING the LDS-bounce epilogue
//      (R5's 128^2 regression was confounded by the scalar scatter epilogue).
//      FM=4 FN=4, 48 MFMA / 8 staged chunks per wave-K-step (density 6 vs 4),
//      1.5x less staging traffic.  Bounce [128][136] (34.8KB); V bounce spans
//      2 heads (row>>6).  Grid 24x16=384.
// ---------------------------------------------------------------------------

#define NB   2
#define SEQ  1024
#define CDIM 1024
#define NH   16
#define HD   64
#define ROWS (NB*SEQ)          // 2048
#define ATT_SCALE 0.125f       // 64^-0.5

typedef __attribute__((ext_vector_type(8))) short bf16x8;
typedef __attribute__((ext_vector_type(4))) float f32x4;

#define MFMA16(a,b,c) __builtin_amdgcn_mfma_f32_16x16x32_bf16((a),(b),(c),0,0,0)

static __device__ __forceinline__ unsigned short f2bf(float f) {
  uint32_t x = __builtin_bit_cast(uint32_t, f);
  return (unsigned short)((x + 0x7fffu + ((x >> 16) & 1u)) >> 16);   // RTN-even
}
static __device__ __forceinline__ float bf2f(unsigned short u) {
  uint32_t x = ((uint32_t)u) << 16;
  return __builtin_bit_cast(float, x);
}

// async global->LDS DMA, 16B/lane; lds dest = wave-uniform base + lane*16
static __device__ __forceinline__ void gl_lds16(const unsigned short* g,
                                                unsigned short* l) {
  __builtin_amdgcn_global_load_lds(
      (const __attribute__((address_space(1))) unsigned int*)g,
      (__attribute__((address_space(3))) unsigned int*)l,
      16, 0, 0);
}

// ---------------------------------------------------------------------------
// K0: fp32 -> bf16 hi/lo split for x and concatenated W = [Wq; Wkv; Wp]
// Vectorized: 4 f32 per thread, packed uint2 stores per plane.
// ---------------------------------------------------------------------------
__global__ __launch_bounds__(256) void k_convert(
    const float* __restrict__ x, const float* __restrict__ Wq,
    const float* __restrict__ Wkv, const float* __restrict__ Wp,
    unsigned short* __restrict__ Xhi, unsigned short* __restrict__ Xlo,
    unsigned short* __restrict__ Whi, unsigned short* __restrict__ Wlo)
{
  const int NX4 = ROWS*CDIM/4;       // 524288
  const int NW4 = 4096*CDIM/4;       // 1048576
  int i = blockIdx.x*256 + threadIdx.x;
  float4 f;
  unsigned short* dh;
  unsigned short* dl;
  size_t o4;
  if (i < NX4) {
    f = ((const float4*)x)[i];
    dh = Xhi; dl = Xlo; o4 = (size_t)i*4;
  } else if (i < NX4 + NW4) {
    int w4 = i - NX4;
    int j = w4 >> 8;                 // row (w4*4 / 1024)
    int c4 = w4 & 255;               // col/4
    const float* ws = (j < 1024) ? Wq + (size_t)j*1024
                    : (j < 3072) ? Wkv + (size_t)(j-1024)*1024
                                 : Wp + (size_t)(j-3072)*1024;
    f = ((const float4*)ws)[c4];
    dh = Whi; dl = Wlo; o4 = (size_t)w4*4;
  } else return;
  float fv[4] = {f.x, f.y, f.z, f.w};
  unsigned int hp[2], lp[2];
  #pragma unroll
  for (int e = 0; e < 2; e++) {
    unsigned short h0 = f2bf(fv[e*2]),   l0 = f2bf(fv[e*2]   - bf2f(h0));
    unsigned short h1 = f2bf(fv[e*2+1]), l1 = f2bf(fv[e*2+1] - bf2f(h1));
    hp[e] = (unsigned)h0 | ((unsigned)h1 << 16);
    lp[e] = (unsigned)l0 | ((unsigned)l1 << 16);
  }
  *(uint2*)(dh + o4) = make_uint2(hp[0], hp[1]);
  *(uint2*)(dl + o4) = make_uint2(lp[0], lp[1]);
}

// ---------------------------------------------------------------------------
// K1: QKV GEMM, standalone.  128x128 tile, 2x2 waves (FM=4, FN=4), BK=32,
// swizzled LDS.  Epilogue: LDS bounce [128][136] -> coalesced uint4 stores.
//   seg 0/1 (Q/K): bounce rows=m -> Q/K[m][n].
//   seg 2 (V):     bounce rows=n (2 heads, transposed) -> Vt[d][m].
// ---------------------------------------------------------------------------
__global__ __launch_bounds__(256) void k_gemm_qkv(
    const unsigned short* __restrict__ Xhi, const unsigned short* __restrict__ Xlo,
    const unsigned short* __restrict__ Whi, const unsigned short* __restrict__ Wlo,
    const float* __restrict__ bq, const float* __restrict__ bkv,
    unsigned short* __restrict__ Qhi, unsigned short* __restrict__ Qlo,
    unsigned short* __restrict__ Khi, unsigned short* __restrict__ Klo,
    unsigned short* __restrict__ Vthi, unsigned short* __restrict__ Vtlo)
{
  __shared__ unsigned short smem[17408];      // staging 32KB; bounce [128][136]
  unsigned short* sAh = smem;                 // 128*32 each
  unsigned short* sAl = smem + 4096;
  unsigned short* sBh = smem + 8192;
  unsigned short* sBl = smem + 12288;
  const int tid = threadIdx.x, lane = tid & 63, wave = tid >> 6;
  const int wm = wave & 1, wn = wave >> 1;
  const int bn = blockIdx.x * 128, bm = blockIdx.y * 128;
  const int r = lane & 15, q = lane >> 4;
  const int crow = lane >> 2;
  const int cgsw = ((lane & 3) ^ ((crow >> 1) & 3)) * 8;
  const int qsw = (q ^ ((r >> 1) & 3)) * 8;

  f32x4 acc[4][4];
  #pragma unroll
  for (int i = 0; i < 4; i++)
    #pragma unroll
    for (int j = 0; j < 4; j++) {
      acc[i][j][0]=0.f; acc[i][j][1]=0.f; acc[i][j][2]=0.f; acc[i][j][3]=0.f;
    }

  for (int k0 = 0; k0 < CDIM; k0 += 32) {
    #pragma unroll
    for (int t = 0; t < 8; t++) {            // TOT=32 chunks / 4 waves
      int c = wave + t*4;
      const unsigned short* gb; unsigned short* sb; int rr, grow;
      if (c < 8)        { gb=Xhi; sb=sAh; rr=c;    grow=bm; }
      else if (c < 16)  { gb=Xlo; sb=sAl; rr=c-8;  grow=bm; }
      else if (c < 24)  { gb=Whi; sb=sBh; rr=c-16; grow=bn; }
      else              { gb=Wlo; sb=sBl; rr=c-24; grow=bn; }
      int row = rr*16 + crow;
      gl_lds16(gb + (size_t)(grow + row)*CDIM + k0 + cgsw, sb + rr*512);
    }
    __syncthreads();
    bf16x8 ah[4], al[4], bh[4], bl[4];
    #pragma unroll
    for (int i = 0; i < 4; i++) {
      int oa = (wm*64 + i*16 + r)*32 + qsw;
      ah[i] = *(const bf16x8*)(sAh + oa);
      al[i] = *(const bf16x8*)(sAl + oa);
    }
    #pragma unroll
    for (int j = 0; j < 4; j++) {
      int ob = (wn*64 + j*16 + r)*32 + qsw;
      bh[j] = *(const bf16x8*)(sBh + ob);
      bl[j] = *(const bf16x8*)(sBl + ob);
    }
    #pragma unroll
    for (int i = 0; i < 4; i++)
      #pragma unroll
      for (int j = 0; j < 4; j++) {
        acc[i][j] = MFMA16(ah[i], bh[j], acc[i][j]);
        acc[i][j] = MFMA16(ah[i], bl[j], acc[i][j]);
        acc[i][j] = MFMA16(al[i], bh[j], acc[i][j]);
      }
    __syncthreads();
  }

  // ---- epilogue: bias+scale, hi/lo split, LDS bounce, coalesced stores
  const int seg = bn >> 10;                       // 0=Q 1=K 2=V
  const float* bias = (seg == 0) ? (bq + bn) : (bkv + (bn - 1024));
  const float scl = (seg == 0) ? ATT_SCALE : 1.0f;
  float bj[4] = { bias[wn*64 + r],      bias[wn*64 + 16 + r],
                  bias[wn*64 + 32 + r], bias[wn*64 + 48 + r] };

  if (seg < 2) {
    unsigned short* dh = (seg == 0) ? Qhi : Khi;
    unsigned short* dl = (seg == 0) ? Qlo : Klo;
    const int ncol = bn & 1023;
    #pragma unroll
    for (int p = 0; p < 2; p++) {
      #pragma unroll
      for (int i = 0; i < 4; i++)
        #pragma unroll
        for (int j = 0; j < 4; j++)
          #pragma unroll
          for (int t = 0; t < 4; t++) {
            int m_l = wm*64 + i*16 + q*4 + t;
            int n_l = wn*64 + j*16 + r;
            float v2 = (acc[i][j][t] + bj[j]) * scl;
            unsigned short hv = f2bf(v2);
            unsigned short val = (p == 0) ? hv : f2bf(v2 - bf2f(hv));
            smem[m_l*136 + n_l] = val;
          }
      __syncthreads();
      unsigned short* dst = (p == 0) ? dh : dl;
      #pragma unroll
      for (int u = 0; u < 8; u++) {
        int s = u*256 + tid;                  // 0..2047
        int m_l = s >> 4, nseg = s & 15;
        uint4 vv = *(const uint4*)(smem + m_l*136 + nseg*8);
        *(uint4*)(dst + (size_t)(bm + m_l)*1024 + ncol + nseg*8) = vv;
      }
      __syncthreads();
    }
  } else {
    // V: transposed bounce rows=n_l (2 heads) -> Vt[((b*NH+h)*HD+d)*SEQ + m]
    const int h0 = (bn - 2048) >> 6;              // first head (even)
    const int b = bm >> 10, mm = bm & 1023;
    #pragma unroll
    for (int p = 0; p < 2; p++) {
      #pragma unroll
      for (int i = 0; i < 4; i++)
        #pragma unroll
        for (int j = 0; j < 4; j++)
          #pragma unroll
          for (int t = 0; t < 4; t++) {
            int m_l = wm*64 + i*16 + q*4 + t;
            int n_l = wn*64 + j*16 + r;           // 0..127 across 2 heads
            float v2 = acc[i][j][t] + bj[j];
            unsigned short hv = f2bf(v2);
            unsigned short val = (p == 0) ? hv : f2bf(v2 - bf2f(hv));
            smem[n_l*136 + m_l] = val;
          }
      __syncthreads();
      unsigned short* dst = (p == 0) ? Vthi : Vtlo;
      #pragma unroll
      for (int u = 0; u < 8; u++) {
        int s = u*256 + tid;                  // 0..2047
        int row = s >> 4, mseg = s & 15;      // row = n_l
        int head = row >> 6, d_l = row & 63;
        uint4 vv = *(const uint4*)(smem + row*136 + mseg*8);
        *(uint4*)(dst + ((size_t)((b*NH + h0 + head)*HD + d_l))*SEQ + mm + mseg*8) = vv;
      }
      __syncthreads();
    }
  }
}

// ---------------------------------------------------------------------------
// Templated NT-GEMM core (split bf16, BK=32, wave grid WM x WN) -- k_gemm_out.
// ---------------------------------------------------------------------------
struct EpiOut {
  const float* bp; float* out;
  __device__ __forceinline__ void operator()(int m, int n, float v) const {
    out[(size_t)m*1024 + n] = v + bp[n];
  }
};

template <int BM, int BN, int WM, int WN, class Epi>
__device__ __forceinline__ void gemm_core(
    const unsigned short* __restrict__ Ahi, const unsigned short* __restrict__ Alo, int lda,
    const unsigned short* __restrict__ Bhi, const unsigned short* __restrict__ Blo, int ldb,
    int K, const Epi& epi)
{
  constexpr int WAVES = WM*WN;
  constexpr int FM = BM/(WM*16), FN = BN/(WN*16);
  constexpr int CA = BM/16, CB = BN/16;
  constexpr int TOT = 2*(CA+CB);
  __shared__ unsigned short sAh[BM*32], sAl[BM*32], sBh[BN*32], sBl[BN*32];
  const int tid  = threadIdx.x;
  const int lane = tid & 63, wave = tid >> 6;
  const int wm = wave % WM, wn = wave / WM;
  const int bn = blockIdx.x * BN, bm = blockIdx.y * BM;
  const int r = lane & 15, q = lane >> 4;
  const int crow = lane >> 2;
  const int cgsw = ((lane & 3) ^ ((crow >> 1) & 3)) * 8;   // swizzled src group
  const int qsw = (q ^ ((r >> 1) & 3)) * 8;                // swizzled read group

  f32x4 acc[FM][FN];
  #pragma unroll
  for (int i = 0; i < FM; i++)
    #pragma unroll
    for (int j = 0; j < FN; j++) {
      acc[i][j][0]=0.f; acc[i][j][1]=0.f; acc[i][j][2]=0.f; acc[i][j][3]=0.f;
    }

  for (int k0 = 0; k0 < K; k0 += 32) {
    #pragma unroll
    for (int t = 0; t < TOT/WAVES; t++) {
      int c = wave + t*WAVES;
      const unsigned short* gb; unsigned short* sb; int rr, grow, ld;
      if (c < CA)            { gb=Ahi; sb=sAh; rr=c;         grow=bm; ld=lda; }
      else if (c < 2*CA)     { gb=Alo; sb=sAl; rr=c-CA;      grow=bm; ld=lda; }
      else if (c < 2*CA+CB)  { gb=Bhi; sb=sBh; rr=c-2*CA;    grow=bn; ld=ldb; }
      else                   { gb=Blo; sb=sBl; rr=c-2*CA-CB; grow=bn; ld=ldb; }
      int row = rr*16 + crow;
      gl_lds16(gb + (size_t)(grow + row)*ld + k0 + cgsw, sb + rr*512);
    }
    __syncthreads();
    bf16x8 ah[FM], al[FM], bh[FN], bl[FN];
    #pragma unroll
    for (int i = 0; i < FM; i++) {
      int oa = (wm*(BM/WM) + i*16 + r)*32 + qsw;
      ah[i] = *(const bf16x8*)(sAh + oa);
      al[i] = *(const bf16x8*)(sAl + oa);
    }
    #pragma unroll
    for (int j = 0; j < FN; j++) {
      int ob = (wn*(BN/WN) + j*16 + r)*32 + qsw;
      bh[j] = *(const bf16x8*)(sBh + ob);
      bl[j] = *(const bf16x8*)(sBl + ob);
    }
    #pragma unroll
    for (int i = 0; i < FM; i++)
      #pragma unroll
      for (int j = 0; j < FN; j++) {
        acc[i][j] = MFMA16(ah[i], bh[j], acc[i][j]);
        acc[i][j] = MFMA16(ah[i], bl[j], acc[i][j]);
        acc[i][j] = MFMA16(al[i], bh[j], acc[i][j]);
      }
    __syncthreads();
  }
  #pragma unroll
  for (int i = 0; i < FM; i++)
    #pragma unroll
    for (int j = 0; j < FN; j++)
      #pragma unroll
      for (int t = 0; t < 4; t++)
        epi(bm + wm*(BM/WM) + i*16 + q*4 + t, bn + wn*(BN/WN) + j*16 + r, acc[i][j][t]);
}

__global__ __launch_bounds__(512) void k_gemm_out(
    const unsigned short* OAhi, const unsigned short* OAlo,
    const unsigned short* Wphi, const unsigned short* Wplo,
    const float* bp, float* out)
{
  EpiOut e{bp, out};
  gemm_core<128,64,4,2>(OAhi, OAlo, CDIM, Wphi, Wplo, CDIM, CDIM, e);
}

// ---------------------------------------------------------------------------
// K23: FUSED softmax+PV.  Block = 32 n-rows x one (b,h); 512 thr (8 waves).
// 16 chunks of 64 m.  K and Vt double-buffered (dseg-swizzled, gl_lds16).
// Wave roles: QK^T n-half = wave>>2, m-tile = wave&3; PV same n-half,
// d-tile = wave&3.  Per chunk: QK^T -> row max (redm dbuf) -> quantize u16
// (global P + bank-swizzled sP) -> PV with online accO rescale via fac[].
// End: S reduce -> invS, F table (16 chunks); accO*invS -> OA hi/lo.
// musd/fac/invS/reds overlay dead sQ space (Q is in regs after chunk 0).
// ---------------------------------------------------------------------------
__global__ __launch_bounds__(512, 4) void k_attn_fused(
    const unsigned short* __restrict__ Qhi, const unsigned short* __restrict__ Qlo,
    const unsigned short* __restrict__ Khi, const unsigned short* __restrict__ Klo,
    const unsigned short* __restrict__ Vthi, const unsigned short* __restrict__ Vtlo,
    unsigned short* __restrict__ P, float* __restrict__ F,
    unsigned short* __restrict__ OAhi, unsigned short* __restrict__ OAlo)
{
  int id = blockIdx.x + 32*(blockIdx.y + 16*blockIdx.z);   // 1024 blocks
  id = (id & 7)*128 + (id >> 3);                           // XCD chunked
  const int nt = id & 31, h = (id >> 5) & 15, b = id >> 9;
  const int n0 = nt*32, col0 = h*HD;
  __shared__ unsigned short sQ[2*2048];        // 8KB; scalars overlaid later
  __shared__ unsigned short sK[2][2*4096];     // 32KB [buf][plane][64m x 64k]
  __shared__ unsigned short sV[2][2*4096];     // 32KB [buf][plane][64d x 64m]
  __shared__ unsigned short sP[32*64];         // 4KB u16, bank-swizzled
  __shared__ float redm[2][8][16];             // 1KB per-chunk wave max
  float* musd  = (float*)sQ;                   // [32][16]  (2048B)
  float* fac   = (float*)(sQ + 1024);          // [32]      (byte 2048)
  float* invSs = (float*)(sQ + 1088);          // [32]      (byte 2176)
  float* redsS = (float*)(sQ + 1152);          // [8][16]   (byte 2304..2816)
  const int tid = threadIdx.x, lane = tid & 63, wave = tid >> 6;
  const int r = lane & 15, q = lane >> 4;
  const int drow = lane >> 3, dseg = (lane & 7) ^ drow;   // DMA swizzle
  const int sw = r & 7;                                   // read swizzle
  const int nf = wave >> 2;      // n-half (QK^T and PV)
  const int mt = wave & 3;       // m-tile (QK^T) / d-tile (PV)
  const size_t qrow0 = (size_t)b*SEQ + n0;
  const size_t krow0 = (size_t)b*SEQ;
  const size_t vt0   = (size_t)(b*NH + h)*HD;

  auto stageK = [&](int c, int buf) {
    #pragma unroll
    for (int u = 0; u < 2; u++) {
      int cc = wave*2 + u;               // 0..15
      int p = cc >> 3, t = cc & 7;
      const unsigned short* g = p ? Klo : Khi;
      gl_lds16(g + (krow0 + (size_t)c*64 + t*8 + drow)*CDIM + col0 + dseg*8,
               sK[buf] + p*4096 + t*512);
    }
  };
  auto stageV = [&](int c, int buf) {
    #pragma unroll
    for (int u = 0; u < 2; u++) {
      int cc = wave*2 + u;
      int p = cc >> 3, t = cc & 7;
      const unsigned short* g = p ? Vtlo : Vthi;
      gl_lds16(g + (vt0 + t*8 + drow)*SEQ + (size_t)c*64 + dseg*8,
               sV[buf] + p*4096 + t*512);
    }
  };

  {   // initial: Q + chunk 0 of K and V
    int p = wave >> 2, t = wave & 3;
    const unsigned short* g = p ? Qlo : Qhi;
    gl_lds16(g + (qrow0 + t*8 + drow)*CDIM + col0 + dseg*8, sQ + p*2048 + t*512);
    stageK(0, 0); stageV(0, 0);
  }
  __syncthreads();

  // Q fragments (one n-half per wave) -> registers for the whole kernel
  bf16x8 qh[2], ql[2];
  #pragma unroll
  for (int ks = 0; ks < 2; ks++) {
    int phys = (nf*16 + r)*64 + (((ks*4 + q) ^ sw))*8;
    qh[ks] = *(const bf16x8*)(sQ + phys);
    ql[ks] = *(const bf16x8*)(sQ + 2048 + phys);
  }

  float m_run = -1e30f, s_run = 0.f;
  f32x4 accO; accO[0]=0.f; accO[1]=0.f; accO[2]=0.f; accO[3]=0.f;
  const size_t pbase = ((size_t)(b*NH + h)*SEQ + n0)*SEQ;

  for (int c = 0; c < 16; c++) {
    const int buf = c & 1;
    // a. QK^T for this wave's (nf, mt)
    bf16x8 kh[2], kl[2];
    #pragma unroll
    for (int ks = 0; ks < 2; ks++) {
      int phys = (mt*16 + r)*64 + (((ks*4 + q) ^ sw))*8;
      kh[ks] = *(const bf16x8*)(sK[buf] + phys);
      kl[ks] = *(const bf16x8*)(sK[buf] + 4096 + phys);
    }
    f32x4 acc; acc[0]=0.f; acc[1]=0.f; acc[2]=0.f; acc[3]=0.f;
    #pragma unroll
    for (int ks = 0; ks < 2; ks++) {
      acc = MFMA16(kh[ks], qh[ks], acc);
      acc = MFMA16(kl[ks], qh[ks], acc);
      acc = MFMA16(kh[ks], ql[ks], acc);
    }
    // b. wave-level row max partials
    {
      float v = fmaxf(fmaxf(acc[0], acc[1]), fmaxf(acc[2], acc[3]));
      v = fmaxf(v, __shfl_xor(v, 16));
      v = fmaxf(v, __shfl_xor(v, 32));
      if (q == 0) redm[buf][wave][r] = v;
    }
    __syncthreads();                     // BARRIER-1
    // d. prefetch next chunk (K and V)
    if (c < 15) { stageK(c+1, buf^1); stageV(c+1, buf^1); }
    // e. chunk max -> quantize -> global P + sP; fac/musd bookkeeping
    {
      const int wg = nf*4;
      float mc = redm[buf][wg][r];
      #pragma unroll
      for (int w2 = 1; w2 < 4; w2++) mc = fmaxf(mc, redm[buf][wg + w2][r]);
      float mnew = fmaxf(m_run, mc);
      if (wave == wg && q == 0) {        // one writer per row
        fac[nf*16 + r] = __expf(m_run - mnew);
        musd[(nf*16 + r)*16 + c] = mnew;
      }
      unsigned s0 = (unsigned)(__expf(acc[0]-mnew)*65535.f + 0.5f);
      unsigned s1 = (unsigned)(__expf(acc[1]-mnew)*65535.f + 0.5f);
      unsigned s2 = (unsigned)(__expf(acc[2]-mnew)*65535.f + 0.5f);
      unsigned s3 = (unsigned)(__expf(acc[3]-mnew)*65535.f + 0.5f);
      uint2 pk = make_uint2(s0 | (s1 << 16), s2 | (s3 << 16));
      const int row = nf*16 + r;
      *(uint2*)(P + pbase + (size_t)row*SEQ + c*64 + mt*16 + q*4) = pk;
      int gw = mt*2 + (q >> 1);                       // 16B group of m
      *(uint2*)(sP + row*64 + ((gw ^ (r & 7)) << 3) + (q & 1)*4) = pk;
      s_run = s_run*__expf(m_run - mnew) + (float)(s0 + s1 + s2 + s3);
      m_run = mnew;
    }
    __syncthreads();                     // BARRIER-2
    // g. PV: rescale accO, then 2 k-steps x 3 MFMA from sP (in-reg dequant) + sV
    {
      float f0 = fac[nf*16 + q*4 + 0];
      float f1 = fac[nf*16 + q*4 + 1];
      float f2 = fac[nf*16 + q*4 + 2];
      float f3 = fac[nf*16 + q*4 + 3];
      accO[0] *= f0; accO[1] *= f1; accO[2] *= f2; accO[3] *= f3;
      #pragma unroll
      for (int kk = 0; kk < 2; kk++) {
        int gr = kk*4 + q;
        uint4 pv4 = *(const uint4*)(sP + (nf*16 + r)*64 + ((gr ^ (r & 7)) << 3));
        unsigned int wds[4] = {pv4.x, pv4.y, pv4.z, pv4.w};
        unsigned int pa_[4], pb_[4];
        #pragma unroll
        for (int e = 0; e < 4; e++) {
          unsigned int lo16 = wds[e] & 0xFFFFu;
          unsigned int hi16 = wds[e] >> 16;
          unsigned int a0 = __builtin_bit_cast(uint32_t, (float)(lo16 & 0xFF00u)) >> 16;
          unsigned int b0 = __builtin_bit_cast(uint32_t, (float)(lo16 & 0x00FFu)) >> 16;
          unsigned int a1 = __builtin_bit_cast(uint32_t, (float)(hi16 & 0xFF00u)) >> 16;
          unsigned int b1 = __builtin_bit_cast(uint32_t, (float)(hi16 & 0x00FFu)) >> 16;
          pa_[e] = a0 | (a1 << 16);
          pb_[e] = b0 | (b1 << 16);
        }
        bf16x8 pa = __builtin_bit_cast(bf16x8, make_uint4(pa_[0],pa_[1],pa_[2],pa_[3]));
        bf16x8 pb = __builtin_bit_cast(bf16x8, make_uint4(pb_[0],pb_[1],pb_[2],pb_[3]));
        int physv = (mt*16 + r)*64 + (((kk*4 + q) ^ sw))*8;
        bf16x8 vh = *(const bf16x8*)(sV[buf] + physv);
        bf16x8 vl = *(const bf16x8*)(sV[buf] + 4096 + physv);
        accO = MFMA16(pa, vh, accO);
        accO = MFMA16(pb, vh, accO);
        accO = MFMA16(pa, vl, accO);
      }
    }
  }

  // ---- final sum reduction, invS + F table
  {
    float s = s_run;
    s += __shfl_xor(s, 16);
    s += __shfl_xor(s, 32);
    if (q == 0) redsS[wave*16 + r] = s;
  }
  __syncthreads();
  if (tid < 32) {
    int row = tid;
    int wg = (row >> 4)*4, rr = row & 15;
    float S = redsS[wg*16 + rr] + redsS[(wg+1)*16 + rr]
            + redsS[(wg+2)*16 + rr] + redsS[(wg+3)*16 + rr];
    float mfin = musd[row*16 + 15];
    float inv = 1.0f / S;
    invSs[row] = inv;
    size_t fb = ((size_t)(b*NH + h)*SEQ + n0 + row)*16;
    #pragma unroll
    for (int c = 0; c < 16; c++)
      F[fb + c] = __expf(musd[row*16 + c] - mfin) * inv;
  }
  __syncthreads();
  // ---- scale + OA store
  {
    float i0 = invSs[nf*16 + q*4 + 0];
    float i1 = invSs[nf*16 + q*4 + 1];
    float i2 = invSs[nf*16 + q*4 + 2];
    float i3 = invSs[nf*16 + q*4 + 3];
    float vals[4] = {accO[0]*i0, accO[1]*i1, accO[2]*i2, accO[3]*i3};
    #pragma unroll
    for (int t = 0; t < 4; t++) {
      int nn = n0 + nf*16 + q*4 + t;
      int d = mt*16 + r;
      size_t o = (size_t)(b*SEQ + nn)*CDIM + h*HD + d;
      unsigned short hb = f2bf(vals[t]);
      OAhi[o] = hb; OAlo[o] = f2bf(vals[t] - bf2f(hb));
    }
  }
}

// ---------------------------------------------------------------------------
// K_attn: dequant-transpose P[b][h][n][m] u16 * F -> attn[b][n][m][h] f32.
// One thread per (b,n,m): 16 coalesced u16 loads + 16 L2-hot F loads,
// 4 contiguous float4 stores.  F has 16 chunks/row (m>>6).
// ---------------------------------------------------------------------------
__global__ __launch_bounds__(256) void k_attn_write(
    const unsigned short* __restrict__ P, const float* __restrict__ F,
    float* __restrict__ attn)
{
  int T = blockIdx.x*256 + threadIdx.x;
  int b = T >> 20, rem = T & 1048575;
  int n = rem >> 10, m = rem & 1023;
  int c = m >> 6;
  const size_t pb = ((size_t)(b*NH)*SEQ + n)*SEQ + m;
  const size_t fb = ((size_t)(b*NH)*SEQ + n)*16 + c;
  float v[16];
  #pragma unroll
  for (int h = 0; h < 16; h++)
    v[h] = (float)P[pb + (size_t)h*SEQ*SEQ] * F[fb + (size_t)h*SEQ*16];
  size_t ob = ((size_t)(b*SEQ + n)*SEQ + m)*16;
  #pragma unroll
  for (int g = 0; g < 4; g++)
    *(float4*)(attn + ob + g*4) = make_float4(v[g*4], v[g*4+1], v[g*4+2], v[g*4+3]);
}

// ---------------------------------------------------------------------------
extern "C" void kernel_launch(void* const* d_in, const int* in_sizes, int n_in,
                              void* d_out, int out_size, void* d_ws, size_t ws_size,
                              hipStream_t stream)
{
  const float* x   = (const float*)d_in[0];
  const float* Wq  = (const float*)d_in[1];
  const float* bq  = (const float*)d_in[2];
  const float* Wkv = (const float*)d_in[3];
  const float* bkv = (const float*)d_in[4];
  const float* Wp  = (const float*)d_in[5];
  const float* bp  = (const float*)d_in[6];

  float* out  = (float*)d_out;
  float* attn = out + (size_t)ROWS*CDIM;

  char* w = (char*)d_ws;
  unsigned short* Xhi  = (unsigned short*)w; w += (size_t)ROWS*CDIM*2;
  unsigned short* Xlo  = (unsigned short*)w; w += (size_t)ROWS*CDIM*2;
  unsigned short* Whi  = (unsigned short*)w; w += (size_t)4096*CDIM*2;
  unsigned short* Wlo  = (unsigned short*)w; w += (size_t)4096*CDIM*2;
  unsigned short* Qhi  = (unsigned short*)w; w += (size_t)ROWS*CDIM*2;
  unsigned short* Qlo  = (unsigned short*)w; w += (size_t)ROWS*CDIM*2;
  unsigned short* Khi  = (unsigned short*)w; w += (size_t)ROWS*CDIM*2;
  unsigned short* Klo  = (unsigned short*)w; w += (size_t)ROWS*CDIM*2;
  unsigned short* Vthi = (unsigned short*)w; w += (size_t)NB*NH*HD*SEQ*2;
  unsigned short* Vtlo = (unsigned short*)w; w += (size_t)NB*NH*HD*SEQ*2;
  unsigned short* OAhi = (unsigned short*)w; w += (size_t)ROWS*CDIM*2;
  unsigned short* OAlo = (unsigned short*)w; w += (size_t)ROWS*CDIM*2;
  unsigned short* P    = (unsigned short*)w; w += (size_t)NB*NH*SEQ*SEQ*2;
  float*          Ftab = (float*)w;          w += (size_t)NB*NH*SEQ*16*4;

  k_convert<<<dim3((ROWS*CDIM/4 + 4096*CDIM/4)/256), 256, 0, stream>>>(
      x, Wq, Wkv, Wp, Xhi, Xlo, Whi, Wlo);

  k_gemm_qkv<<<dim3(3072/128, 2048/128), 256, 0, stream>>>(
      Xhi, Xlo, Whi, Wlo, bq, bkv, Qhi, Qlo, Khi, Klo, Vthi, Vtlo);

  k_attn_fused<<<dim3(SEQ/32, NH, NB), 512, 0, stream>>>(
      Qhi, Qlo, Khi, Klo, Vthi, Vtlo, P, Ftab, OAhi, OAlo);

  k_gemm_out<<<dim3(1024/64, 2048/128), 512, 0, stream>>>(
      OAhi, OAlo, Whi + (size_t)3072*CDIM, Wlo + (size_t)3072*CDIM, bp, out);

  k_attn_write<<<dim3((NB*SEQ*SEQ)/256), 256, 0, stream>>>(P, Ftab, attn);
}